// Round 3
// baseline (696.592 us; speedup 1.0000x reference)
//
#include <hip/hip_runtime.h>
#include <math.h>

typedef _Float16 f16x8 __attribute__((ext_vector_type(8)));
typedef float    f32x4 __attribute__((ext_vector_type(4)));

#define FEAT_H 128
#define FEAT_W 352
#define FPIX   (FEAT_H * FEAT_W)   // 45056
#define BEV    320
#define NCELL  (BEV * BEV)         // 102400
#define CH     96
#define PD     322                 // padded spatial dim
#define PPIX   (PD * PD)           // 103684

// ---- workspace layout (float offsets) ----
#define N_PADF    (2 * PPIX * CH / 2)            // 9,953,664 floats (f16 buffer)
#define OFF_BUFB  0
#define OFF_WT    (N_PADF)                       // f16 2*9*96*96 = 82,944 floats
#define OFF_HW    (OFF_WT + 82944)               // 64*64 fp32
#define OFF_BASE  (OFF_HW + 4096)                // 3*64 fp32 (pad 256)
#define OFF_BUFA  (OFF_BASE + 256)               // f16 padded conv1 input

// ---------------------------------------------------------------------------
// hW = dw2 @ sw1 (64x64); base[h] = (db2 + he[h]) @ sw1 + sb1
// ---------------------------------------------------------------------------
__global__ void k_precompute(const float* __restrict__ dw2, const float* __restrict__ sw1,
                             const float* __restrict__ db2, const float* __restrict__ he,
                             const float* __restrict__ sb1,
                             float* __restrict__ hW, float* __restrict__ baseT) {
    const int t = threadIdx.x;
    for (int idx = t; idx < 64 * 64; idx += 256) {
        int j = idx >> 6, k = idx & 63;
        float s = 0.f;
        for (int c = 0; c < CH; c++) s = fmaf(dw2[j * CH + c], sw1[c * 64 + k], s);
        hW[idx] = s;
    }
    for (int idx = t; idx < 3 * 64; idx += 256) {
        int h = idx >> 6, k = idx & 63;
        float s = sb1[k];
        for (int c = 0; c < CH; c++) s = fmaf(db2[c] + he[h * CH + c], sw1[c * 64 + k], s);
        baseT[idx] = s;
    }
}

// ---------------------------------------------------------------------------
// Weight prep: wt[cv][tap][oc][ic] (f16)  from  w[oc][ic][3][3] (fp32)
// ---------------------------------------------------------------------------
__global__ void k_wprep(const float* __restrict__ w1, const float* __restrict__ w2,
                        _Float16* __restrict__ wt) {
    int idx = blockIdx.x * 256 + threadIdx.x;       // 2*9*96*96 = 165888
    if (idx >= 165888) return;
    int cv = idx / 82944; int r = idx - cv * 82944;
    int tap = r / 9216;   int rr = r - tap * 9216;
    int oc = rr / 96;     int ic = rr - oc * 96;
    const float* src = cv ? w2 : w1;
    wt[idx] = (_Float16)src[(oc * 96 + ic) * 9 + tap];
}

// ---------------------------------------------------------------------------
// Zero the 1-pixel border of a padded f16 HWC buffer [2][322][322][96]
// ---------------------------------------------------------------------------
__global__ void k_border(_Float16* __restrict__ buf) {
    int idx = blockIdx.x * 256 + threadIdx.x;       // 2*1284 = 2568 border pixels
    if (idx >= 2568) return;
    int img = idx / 1284; int p = idx - img * 1284;
    int row, col;
    if (p < 322)      { row = 0;           col = p; }
    else if (p < 644) { row = 321;         col = p - 322; }
    else if (p < 964) { row = p - 644 + 1; col = 0; }
    else              { row = p - 964 + 1; col = 321; }
    _Float16* q = buf + ((size_t)(img * PD + row) * PD + col) * CH;
    f16x8 z = {};
    #pragma unroll
    for (int c8 = 0; c8 < 12; ++c8) *(f16x8*)(q + c8 * 8) = z;
}

// ---------------------------------------------------------------------------
// featS[b][pix][64] = feat[b][:][pix] @ sw1
// ---------------------------------------------------------------------------
__global__ __launch_bounds__(64) void k_feats(const float* __restrict__ feat,
                                              const float* __restrict__ sw1,
                                              float* __restrict__ featS) {
    const int t = threadIdx.x;
    const int pb = blockIdx.x * 64;
    const int b = blockIdx.y;
    __shared__ float ld[CH * 64];
    const float* fp = feat + (size_t)b * CH * FPIX + pb;
    #pragma unroll 8
    for (int c = 0; c < CH; c++) ld[c * 64 + t] = fp[(size_t)c * FPIX + t];
    __syncthreads();

    float acc[64];
    #pragma unroll
    for (int k = 0; k < 64; k++) acc[k] = 0.f;
    for (int c = 0; c < CH; c++) {
        float x = ld[c * 64 + t];
        const float4* wr = (const float4*)(sw1 + c * 64);
        #pragma unroll
        for (int k4 = 0; k4 < 16; k4++) {
            float4 w = wr[k4];
            acc[4 * k4 + 0] = fmaf(x, w.x, acc[4 * k4 + 0]);
            acc[4 * k4 + 1] = fmaf(x, w.y, acc[4 * k4 + 1]);
            acc[4 * k4 + 2] = fmaf(x, w.z, acc[4 * k4 + 2]);
            acc[4 * k4 + 3] = fmaf(x, w.w, acc[4 * k4 + 3]);
        }
    }
    float4* op = (float4*)(featS + ((size_t)b * FPIX + pb + t) * 64);
    #pragma unroll
    for (int k4 = 0; k4 < 16; k4++)
        op[k4] = make_float4(acc[4 * k4 + 0], acc[4 * k4 + 1], acc[4 * k4 + 2], acc[4 * k4 + 3]);
}

// ---------------------------------------------------------------------------
// Lift -> padded HWC f16 buffer (conv1 input), interior pixels only.
// ---------------------------------------------------------------------------
__global__ __launch_bounds__(256, 3) void k_lift(const float* __restrict__ feat,
                                                 const float* __restrict__ featS,
                                                 const float* __restrict__ l2i,
                                                 const float* __restrict__ dw1,
                                                 const float* __restrict__ db1,
                                                 const float* __restrict__ sw2,
                                                 const float* __restrict__ sb2,
                                                 const float* __restrict__ hW,
                                                 const float* __restrict__ baseT,
                                                 _Float16* __restrict__ out) {
    const int n = blockIdx.x * 256 + threadIdx.x;
    const int b = blockIdx.y;
    const int i = n / BEV, j = n % BEV;
    const float px = ((j + 0.5f) / 320.0f) * 102.4f - 51.2f;
    const float py = ((i + 0.5f) / 320.0f) * 102.4f - 51.2f;
    const float* M = l2i + b * 16;
    const float m00 = M[0], m01 = M[1], m02 = M[2], m03 = M[3];
    const float m10 = M[4], m11 = M[5], m12 = M[6], m13 = M[7];
    const float m20 = M[8], m21 = M[9], m22 = M[10], m23 = M[11];

    const float* fSb = featS + (size_t)b * FPIX * 64;

    float logit[3];
    int   ti[3][4];
    float tw[3][4];

    #pragma unroll
    for (int h = 0; h < 3; h++) {
        logit[h] = -INFINITY;
        const float z = (float)h;
        float p0 = m03 + m00 * px + m01 * py + m02 * z;
        float p1 = m13 + m10 * px + m11 * py + m12 * z;
        float dep = m23 + m20 * px + m21 * py + m22 * z;
        float dv = fmaxf(dep, 1e-5f);
        float u = p0 / dv, v = p1 / dv;
        float gx = (u / 351.0f) * 2.0f - 1.0f;
        float gy = (v / 127.0f) * 2.0f - 1.0f;
        bool valid = (dep > 1e-3f) && (fabsf(gx) <= 1.0f) && (fabsf(gy) <= 1.0f);
        if (!valid) continue;

        float xs = (gx + 1.0f) * 0.5f * 351.0f;
        float ys = (gy + 1.0f) * 0.5f * 127.0f;
        float xf = floorf(xs), yf = floorf(ys);
        int x0 = (int)xf, y0 = (int)yf;
        float wx = xs - xf, wy = ys - yf;
        int x1 = (x0 < FEAT_W - 1) ? x0 + 1 : x0;
        int y1 = (y0 < FEAT_H - 1) ? y0 + 1 : y0;
        ti[h][0] = y0 * FEAT_W + x0;
        ti[h][1] = y0 * FEAT_W + x1;
        ti[h][2] = y1 * FEAT_W + x0;
        ti[h][3] = y1 * FEAT_W + x1;
        tw[h][0] = (1.f - wx) * (1.f - wy);
        tw[h][1] = wx * (1.f - wy);
        tw[h][2] = (1.f - wx) * wy;
        tw[h][3] = wx * wy;

        float hid[64];
        {
            const float* bs = baseT + h * 64;
            #pragma unroll
            for (int k = 0; k < 64; k++) hid[k] = bs[k];
        }
        #pragma unroll
        for (int t = 0; t < 4; t++) {
            const float wt = tw[h][t];
            const float4* p = (const float4*)(fSb + (size_t)ti[h][t] * 64);
            #pragma unroll
            for (int k4 = 0; k4 < 16; k4++) {
                float4 vv = p[k4];
                hid[4 * k4 + 0] = fmaf(wt, vv.x, hid[4 * k4 + 0]);
                hid[4 * k4 + 1] = fmaf(wt, vv.y, hid[4 * k4 + 1]);
                hid[4 * k4 + 2] = fmaf(wt, vv.z, hid[4 * k4 + 2]);
                hid[4 * k4 + 3] = fmaf(wt, vv.w, hid[4 * k4 + 3]);
            }
        }
        const float dl = log1pf(fmaxf(dep, 1e-3f));
        #pragma unroll 4
        for (int jj = 0; jj < 64; jj++) {
            float hd = fmaxf(fmaf(dl, dw1[jj], db1[jj]), 0.f);
            const float4* hr = (const float4*)(hW + jj * 64);
            #pragma unroll
            for (int k4 = 0; k4 < 16; k4++) {
                float4 wv = hr[k4];
                hid[4 * k4 + 0] = fmaf(hd, wv.x, hid[4 * k4 + 0]);
                hid[4 * k4 + 1] = fmaf(hd, wv.y, hid[4 * k4 + 1]);
                hid[4 * k4 + 2] = fmaf(hd, wv.z, hid[4 * k4 + 2]);
                hid[4 * k4 + 3] = fmaf(hd, wv.w, hid[4 * k4 + 3]);
            }
        }
        float lg = sb2[0];
        const float4* s2 = (const float4*)sw2;
        #pragma unroll
        for (int k4 = 0; k4 < 16; k4++) {
            float4 wv = s2[k4];
            lg = fmaf(fmaxf(hid[4 * k4 + 0], 0.f), wv.x, lg);
            lg = fmaf(fmaxf(hid[4 * k4 + 1], 0.f), wv.y, lg);
            lg = fmaf(fmaxf(hid[4 * k4 + 2], 0.f), wv.z, lg);
            lg = fmaf(fmaxf(hid[4 * k4 + 3], 0.f), wv.w, lg);
        }
        logit[h] = lg;
    }

    float mx = fmaxf(logit[0], fmaxf(logit[1], logit[2]));
    float wh[3] = {0.f, 0.f, 0.f};
    if (mx > -INFINITY) {
        float s = 0.f;
        #pragma unroll
        for (int h = 0; h < 3; h++) {
            if (logit[h] > -INFINITY) { wh[h] = expf(logit[h] - mx); s += wh[h]; }
        }
        float inv = 1.0f / s;
        wh[0] *= inv; wh[1] *= inv; wh[2] *= inv;
    }

    float acc[CH];
    #pragma unroll
    for (int c = 0; c < CH; c++) acc[c] = 0.f;
    const float* fB = feat + (size_t)b * CH * FPIX;
    #pragma unroll
    for (int h = 0; h < 3; h++) {
        if (wh[h] > 0.f) {
            const float w0 = tw[h][0], w1 = tw[h][1], w2 = tw[h][2], w3 = tw[h][3];
            const int i0 = ti[h][0], i1 = ti[h][1], i2 = ti[h][2], i3 = ti[h][3];
            const float whh = wh[h];
            for (int c = 0; c < CH; c++) {
                const float* p = fB + (size_t)c * FPIX;
                float sv = w0 * p[i0] + w1 * p[i1] + w2 * p[i2] + w3 * p[i3];
                acc[c] = fmaf(whh, sv, acc[c]);
            }
        }
    }
    _Float16* op = out + ((size_t)(b * PD + i + 1) * PD + (j + 1)) * CH;
    #pragma unroll
    for (int c8 = 0; c8 < 12; ++c8) {
        f16x8 v;
        #pragma unroll
        for (int k = 0; k < 8; ++k) v[k] = (_Float16)acc[c8 * 8 + k];
        *(f16x8*)(op + c8 * 8) = v;
    }
}

// ---------------------------------------------------------------------------
// Conv 3x3 + BN + ReLU, f16 MFMA implicit GEMM, NO LDS staging, no K-loop
// barriers. Block: 8 rows x 32 cols; wave = 2 rows = 4 M-tiles x 6 N-tiles.
// A and B fragments read directly from global (L1/L2-cached), fully unrolled
// 27-step K-loop so the scheduler prefetches ahead.
// MODE 0: out padded HWC f16.  MODE 1: out CHW fp32 (2-pass LDS transpose).
// ---------------------------------------------------------------------------
template<int MODE>
__global__ __launch_bounds__(256, 3) void k_conv_mfma(
        const _Float16* __restrict__ in, const _Float16* __restrict__ wt,
        const float* __restrict__ bng, const float* __restrict__ bnb,
        const float* __restrict__ bnm, const float* __restrict__ bnv,
        void* __restrict__ outv) {
    __shared__ float st[128 * 97];   // MODE 1 transpose only (dead in MODE 0)
    const int tid = threadIdx.x;
    const int w = tid >> 6, lane = tid & 63, q = lane >> 4, n = lane & 15;
    const int x0 = blockIdx.x * 32, y0 = blockIdx.y * 8, b = blockIdx.z;
    const _Float16* inb = in + (size_t)b * PPIX * CH;

    f32x4 acc[4][6];
    #pragma unroll
    for (int mt = 0; mt < 4; mt++)
        #pragma unroll
        for (int nt = 0; nt < 6; nt++) acc[mt][nt] = (f32x4){0.f, 0.f, 0.f, 0.f};

    // wave w covers output rows y0+2w .. y0+2w+1 (padded rows +1)
    const _Float16* abase = inb + ((size_t)(y0 + 2 * w) * PD + x0 + n) * CH + q * 8;
    const _Float16* bbase = wt + n * CH + q * 8;

    #pragma unroll
    for (int r = 0; r < 3; ++r) {
        #pragma unroll
        for (int s = 0; s < 3; ++s) {
            #pragma unroll
            for (int kc = 0; kc < 3; ++kc) {
                const int koff = kc * 32;
                f16x8 bf[6];
                #pragma unroll
                for (int nt = 0; nt < 6; ++nt)
                    bf[nt] = *(const f16x8*)(bbase + (size_t)(r * 3 + s) * CH * CH
                                             + nt * 16 * CH + koff);
                f16x8 af[4];
                #pragma unroll
                for (int mt = 0; mt < 4; ++mt) {
                    const int mrow = mt >> 1, mcol = mt & 1;
                    af[mt] = *(const f16x8*)(abase + ((mrow + r) * PD + mcol * 16 + s) * CH + koff);
                }
                #pragma unroll
                for (int nt = 0; nt < 6; ++nt)
                    #pragma unroll
                    for (int mt = 0; mt < 4; ++mt)
                        acc[mt][nt] = __builtin_amdgcn_mfma_f32_16x16x32_f16(
                                          af[mt], bf[nt], acc[mt][nt], 0, 0, 0);
            }
        }
    }

    // BN params per nt (oc = nt*16+n)
    float sc[6], sh[6];
    #pragma unroll
    for (int nt = 0; nt < 6; ++nt) {
        int oc = nt * 16 + n;
        sc[nt] = bng[oc] * rsqrtf(bnv[oc] + 1e-3f);
        sh[nt] = fmaf(-bnm[oc], sc[nt], bnb[oc]);
    }

    if (MODE == 0) {
        _Float16* outb = (_Float16*)outv + (size_t)b * PPIX * CH;
        #pragma unroll
        for (int mt = 0; mt < 4; ++mt) {
            const int mrow = mt >> 1, mcol = mt & 1;
            const int orow = y0 + 2 * w + mrow + 1;
            #pragma unroll
            for (int rg = 0; rg < 4; ++rg) {
                const int ocol = x0 + mcol * 16 + q * 4 + rg + 1;
                _Float16* op = outb + ((size_t)orow * PD + ocol) * CH + n;
                #pragma unroll
                for (int nt = 0; nt < 6; ++nt)
                    op[nt * 16] = (_Float16)fmaxf(fmaf(acc[mt][nt][rg], sc[nt], sh[nt]), 0.f);
            }
        }
    } else {
        float* outb = (float*)outv + (size_t)b * CH * NCELL;
        #pragma unroll
        for (int p = 0; p < 2; ++p) {
            __syncthreads();
            if ((w >> 1) == p) {
                const int wl = w & 1;
                #pragma unroll
                for (int mt = 0; mt < 4; ++mt) {
                    const int mrow = mt >> 1, mcol = mt & 1;
                    const int prow = wl * 2 + mrow;   // 0..3 local row in this pass
                    #pragma unroll
                    for (int rg = 0; rg < 4; ++rg) {
                        const int pix = prow * 32 + mcol * 16 + q * 4 + rg;
                        #pragma unroll
                        for (int nt = 0; nt < 6; ++nt)
                            st[pix * 97 + nt * 16 + n] =
                                fmaxf(fmaf(acc[mt][nt][rg], sc[nt], sh[nt]), 0.f);
                    }
                }
            }
            __syncthreads();
            const int seg = tid >> 5, l = tid & 31;
            #pragma unroll 4
            for (int i = 0; i < 48; ++i) {
                const int idx = seg * 48 + i;
                const int oc = idx >> 2, rr = idx & 3;
                outb[(size_t)oc * NCELL + (y0 + p * 4 + rr) * BEV + x0 + l] =
                    st[(rr * 32 + l) * 97 + oc];
            }
        }
    }
}

// ---------------------------------------------------------------------------
extern "C" void kernel_launch(void* const* d_in, const int* in_sizes, int n_in,
                              void* d_out, int out_size, void* d_ws, size_t ws_size,
                              hipStream_t stream) {
    const float* feat = (const float*)d_in[0];
    const float* l2i  = (const float*)d_in[1];
    const float* he   = (const float*)d_in[2];
    const float* dw1  = (const float*)d_in[3];
    const float* db1  = (const float*)d_in[4];
    const float* dw2  = (const float*)d_in[5];
    const float* db2  = (const float*)d_in[6];
    const float* sw1  = (const float*)d_in[7];
    const float* sb1  = (const float*)d_in[8];
    const float* sw2  = (const float*)d_in[9];
    const float* sb2  = (const float*)d_in[10];
    const float* c1w  = (const float*)d_in[11];
    const float* bn1g = (const float*)d_in[12];
    const float* bn1b = (const float*)d_in[13];
    const float* bn1m = (const float*)d_in[14];
    const float* bn1v = (const float*)d_in[15];
    const float* c2w  = (const float*)d_in[16];
    const float* bn2g = (const float*)d_in[17];
    const float* bn2b = (const float*)d_in[18];
    const float* bn2m = (const float*)d_in[19];
    const float* bn2v = (const float*)d_in[20];

    float* ws = (float*)d_ws;
    float*     featS = ws + OFF_BUFB;               // aliases bufB (dead before conv1)
    _Float16*  bufB  = (_Float16*)(ws + OFF_BUFB);
    _Float16*  wtp   = (_Float16*)(ws + OFF_WT);
    float*     hW    = ws + OFF_HW;
    float*     baseT = ws + OFF_BASE;
    _Float16*  bufA  = (_Float16*)(ws + OFF_BUFA);
    _Float16*  wt1   = wtp;
    _Float16*  wt2   = wtp + 82944;

    hipLaunchKernelGGL(k_precompute, dim3(1), dim3(256), 0, stream,
                       dw2, sw1, db2, he, sb1, hW, baseT);
    hipLaunchKernelGGL(k_wprep, dim3(648), dim3(256), 0, stream, c1w, c2w, wtp);
    hipLaunchKernelGGL(k_feats, dim3(FPIX / 64, 2), dim3(64), 0, stream,
                       feat, sw1, featS);
    hipLaunchKernelGGL(k_border, dim3(11), dim3(256), 0, stream, bufA);
    hipLaunchKernelGGL(k_lift, dim3(NCELL / 256, 2), dim3(256), 0, stream,
                       feat, featS, l2i, dw1, db1, sw2, sb2, hW, baseT, bufA);
    hipLaunchKernelGGL(k_border, dim3(11), dim3(256), 0, stream, bufB);
    hipLaunchKernelGGL((k_conv_mfma<0>), dim3(10, 40, 2), dim3(256), 0, stream,
                       bufA, wt1, bn1g, bn1b, bn1m, bn1v, (void*)bufB);
    hipLaunchKernelGGL((k_conv_mfma<1>), dim3(10, 40, 2), dim3(256), 0, stream,
                       bufB, wt2, bn2g, bn2b, bn2m, bn2v, d_out);
}

// Round 4
// 454.424 us; speedup vs baseline: 1.5329x; 1.5329x over previous
//
#include <hip/hip_runtime.h>
#include <math.h>

typedef _Float16 f16x8 __attribute__((ext_vector_type(8)));
typedef _Float16 f16x4 __attribute__((ext_vector_type(4)));
typedef float    f32x4 __attribute__((ext_vector_type(4)));

#define FEAT_H 128
#define FEAT_W 352
#define FPIX   (FEAT_H * FEAT_W)   // 45056
#define BEV    320
#define NCELL  (BEV * BEV)         // 102400
#define CH     96
#define PD     322                 // padded spatial dim
#define PPIX   (PD * PD)           // 103684

// ---- workspace layout (float offsets) ----
// bufB f16 [2][PPIX][96] at 0. featS16/featH16 alias inside bufB (dead before
// conv1 writes bufB; k_border(bufB) runs only after k_lift).
#define N_PADF    (2 * PPIX * CH / 2)            // 9,953,664 floats
#define OFF_BUFB  0
#define OFF_FS    0                              // featS16: 2*45056*64 f16 = 2,883,584 fl
#define OFF_FH    2883584                        // featH16: 2*45056*96 f16 = 4,325,376 fl
#define OFF_WT    (N_PADF)                       // f16 2*9*96*96 = 82,944 floats
#define OFF_HW    (OFF_WT + 82944)               // 64*64 fp32
#define OFF_BASE  (OFF_HW + 4096)                // 3*64 fp32 (pad 256)
#define OFF_BUFA  (OFF_BASE + 256)               // f16 padded conv1 input

// ---------------------------------------------------------------------------
// hW = dw2 @ sw1 (64x64); base[h] = (db2 + he[h]) @ sw1 + sb1
// ---------------------------------------------------------------------------
__global__ void k_precompute(const float* __restrict__ dw2, const float* __restrict__ sw1,
                             const float* __restrict__ db2, const float* __restrict__ he,
                             const float* __restrict__ sb1,
                             float* __restrict__ hW, float* __restrict__ baseT) {
    const int t = threadIdx.x;
    for (int idx = t; idx < 64 * 64; idx += 256) {
        int j = idx >> 6, k = idx & 63;
        float s = 0.f;
        for (int c = 0; c < CH; c++) s = fmaf(dw2[j * CH + c], sw1[c * 64 + k], s);
        hW[idx] = s;
    }
    for (int idx = t; idx < 3 * 64; idx += 256) {
        int h = idx >> 6, k = idx & 63;
        float s = sb1[k];
        for (int c = 0; c < CH; c++) s = fmaf(db2[c] + he[h * CH + c], sw1[c * 64 + k], s);
        baseT[idx] = s;
    }
}

// ---------------------------------------------------------------------------
// Weight prep: wt[cv][tap][oc][ic] (f16)  from  w[oc][ic][3][3] (fp32)
// ---------------------------------------------------------------------------
__global__ void k_wprep(const float* __restrict__ w1, const float* __restrict__ w2,
                        _Float16* __restrict__ wt) {
    int idx = blockIdx.x * 256 + threadIdx.x;       // 2*9*96*96 = 165888
    if (idx >= 165888) return;
    int cv = idx / 82944; int r = idx - cv * 82944;
    int tap = r / 9216;   int rr = r - tap * 9216;
    int oc = rr / 96;     int ic = rr - oc * 96;
    const float* src = cv ? w2 : w1;
    wt[idx] = (_Float16)src[(oc * 96 + ic) * 9 + tap];
}

// ---------------------------------------------------------------------------
// Zero the 1-pixel border of a padded f16 HWC buffer [2][322][322][96]
// ---------------------------------------------------------------------------
__global__ void k_border(_Float16* __restrict__ buf) {
    int idx = blockIdx.x * 256 + threadIdx.x;       // 2*1284 = 2568 border pixels
    if (idx >= 2568) return;
    int img = idx / 1284; int p = idx - img * 1284;
    int row, col;
    if (p < 322)      { row = 0;           col = p; }
    else if (p < 644) { row = 321;         col = p - 322; }
    else if (p < 964) { row = p - 644 + 1; col = 0; }
    else              { row = p - 964 + 1; col = 321; }
    _Float16* q = buf + ((size_t)(img * PD + row) * PD + col) * CH;
    f16x8 z = {};
    #pragma unroll
    for (int c8 = 0; c8 < 12; ++c8) *(f16x8*)(q + c8 * 8) = z;
}

// ---------------------------------------------------------------------------
// k_feats: featS16[b][pix][64] = f16(feat[b][:][pix] @ sw1)
//          featH16[b][pix][96] = f16(feat[b][:][pix])   (CHW -> HWC transpose)
// ---------------------------------------------------------------------------
__global__ __launch_bounds__(64) void k_feats(const float* __restrict__ feat,
                                              const float* __restrict__ sw1,
                                              _Float16* __restrict__ featS,
                                              _Float16* __restrict__ featH) {
    const int t = threadIdx.x;
    const int pb = blockIdx.x * 64;
    const int b = blockIdx.y;
    __shared__ float ld[CH * 64];
    const float* fp = feat + (size_t)b * CH * FPIX + pb;
    #pragma unroll 8
    for (int c = 0; c < CH; c++) ld[c * 64 + t] = fp[(size_t)c * FPIX + t];
    __syncthreads();

    float acc[64];
    #pragma unroll
    for (int k = 0; k < 64; k++) acc[k] = 0.f;
    for (int c = 0; c < CH; c++) {
        float x = ld[c * 64 + t];
        const float4* wr = (const float4*)(sw1 + c * 64);
        #pragma unroll
        for (int k4 = 0; k4 < 16; k4++) {
            float4 w = wr[k4];
            acc[4 * k4 + 0] = fmaf(x, w.x, acc[4 * k4 + 0]);
            acc[4 * k4 + 1] = fmaf(x, w.y, acc[4 * k4 + 1]);
            acc[4 * k4 + 2] = fmaf(x, w.z, acc[4 * k4 + 2]);
            acc[4 * k4 + 3] = fmaf(x, w.w, acc[4 * k4 + 3]);
        }
    }
    _Float16* opS = featS + ((size_t)b * FPIX + pb + t) * 64;
    #pragma unroll
    for (int k8 = 0; k8 < 8; k8++) {
        f16x8 v;
        #pragma unroll
        for (int e = 0; e < 8; e++) v[e] = (_Float16)acc[k8 * 8 + e];
        *(f16x8*)(opS + k8 * 8) = v;
    }
    _Float16* opH = featH + ((size_t)b * FPIX + pb + t) * 96;
    #pragma unroll
    for (int c8 = 0; c8 < 12; c8++) {
        f16x8 v;
        #pragma unroll
        for (int e = 0; e < 8; e++) v[e] = (_Float16)ld[(c8 * 8 + e) * 64 + t];
        *(f16x8*)(opH + c8 * 8) = v;
    }
}

// ---------------------------------------------------------------------------
// Lift -> padded HWC f16 buffer (conv1 input). Gathers from f16 featS/featH.
// ---------------------------------------------------------------------------
__global__ __launch_bounds__(128) void k_lift(const _Float16* __restrict__ featS,
                                              const _Float16* __restrict__ featH,
                                              const float* __restrict__ l2i,
                                              const float* __restrict__ dw1,
                                              const float* __restrict__ db1,
                                              const float* __restrict__ sw2,
                                              const float* __restrict__ sb2,
                                              const float* __restrict__ hW,
                                              const float* __restrict__ baseT,
                                              _Float16* __restrict__ out) {
    const int n = blockIdx.x * 128 + threadIdx.x;
    const int b = blockIdx.y;
    const int i = n / BEV, j = n % BEV;
    const float px = ((j + 0.5f) / 320.0f) * 102.4f - 51.2f;
    const float py = ((i + 0.5f) / 320.0f) * 102.4f - 51.2f;
    const float* M = l2i + b * 16;
    const float m00 = M[0], m01 = M[1], m02 = M[2], m03 = M[3];
    const float m10 = M[4], m11 = M[5], m12 = M[6], m13 = M[7];
    const float m20 = M[8], m21 = M[9], m22 = M[10], m23 = M[11];

    const _Float16* fSb = featS + (size_t)b * FPIX * 64;
    const _Float16* fHb = featH + (size_t)b * FPIX * 96;

    float logit[3];
    int   ti[3][4];
    float tw[3][4];

    #pragma unroll
    for (int h = 0; h < 3; h++) {
        logit[h] = -INFINITY;
        const float z = (float)h;
        float p0 = m03 + m00 * px + m01 * py + m02 * z;
        float p1 = m13 + m10 * px + m11 * py + m12 * z;
        float dep = m23 + m20 * px + m21 * py + m22 * z;
        float dv = fmaxf(dep, 1e-5f);
        float u = p0 / dv, v = p1 / dv;
        float gx = (u / 351.0f) * 2.0f - 1.0f;
        float gy = (v / 127.0f) * 2.0f - 1.0f;
        bool valid = (dep > 1e-3f) && (fabsf(gx) <= 1.0f) && (fabsf(gy) <= 1.0f);
        if (!valid) continue;

        float xs = (gx + 1.0f) * 0.5f * 351.0f;
        float ys = (gy + 1.0f) * 0.5f * 127.0f;
        float xf = floorf(xs), yf = floorf(ys);
        int x0 = (int)xf, y0 = (int)yf;
        float wx = xs - xf, wy = ys - yf;
        int x1 = (x0 < FEAT_W - 1) ? x0 + 1 : x0;
        int y1 = (y0 < FEAT_H - 1) ? y0 + 1 : y0;
        ti[h][0] = y0 * FEAT_W + x0;
        ti[h][1] = y0 * FEAT_W + x1;
        ti[h][2] = y1 * FEAT_W + x0;
        ti[h][3] = y1 * FEAT_W + x1;
        tw[h][0] = (1.f - wx) * (1.f - wy);
        tw[h][1] = wx * (1.f - wy);
        tw[h][2] = (1.f - wx) * wy;
        tw[h][3] = wx * wy;

        float hid[64];
        {
            const float* bs = baseT + h * 64;
            #pragma unroll
            for (int k = 0; k < 64; k++) hid[k] = bs[k];
        }
        #pragma unroll
        for (int t = 0; t < 4; t++) {
            const float wt = tw[h][t];
            const f16x8* p = (const f16x8*)(fSb + (size_t)ti[h][t] * 64);
            #pragma unroll
            for (int k8 = 0; k8 < 8; k8++) {
                f16x8 vv = p[k8];
                #pragma unroll
                for (int e = 0; e < 8; e++)
                    hid[k8 * 8 + e] = fmaf(wt, (float)vv[e], hid[k8 * 8 + e]);
            }
        }
        const float dl = log1pf(fmaxf(dep, 1e-3f));
        #pragma unroll 4
        for (int jj = 0; jj < 64; jj++) {
            float hd = fmaxf(fmaf(dl, dw1[jj], db1[jj]), 0.f);
            const float4* hr = (const float4*)(hW + jj * 64);
            #pragma unroll
            for (int k4 = 0; k4 < 16; k4++) {
                float4 wv = hr[k4];
                hid[4 * k4 + 0] = fmaf(hd, wv.x, hid[4 * k4 + 0]);
                hid[4 * k4 + 1] = fmaf(hd, wv.y, hid[4 * k4 + 1]);
                hid[4 * k4 + 2] = fmaf(hd, wv.z, hid[4 * k4 + 2]);
                hid[4 * k4 + 3] = fmaf(hd, wv.w, hid[4 * k4 + 3]);
            }
        }
        float lg = sb2[0];
        const float4* s2 = (const float4*)sw2;
        #pragma unroll
        for (int k4 = 0; k4 < 16; k4++) {
            float4 wv = s2[k4];
            lg = fmaf(fmaxf(hid[4 * k4 + 0], 0.f), wv.x, lg);
            lg = fmaf(fmaxf(hid[4 * k4 + 1], 0.f), wv.y, lg);
            lg = fmaf(fmaxf(hid[4 * k4 + 2], 0.f), wv.z, lg);
            lg = fmaf(fmaxf(hid[4 * k4 + 3], 0.f), wv.w, lg);
        }
        logit[h] = lg;
    }

    float mx = fmaxf(logit[0], fmaxf(logit[1], logit[2]));
    float wh[3] = {0.f, 0.f, 0.f};
    if (mx > -INFINITY) {
        float s = 0.f;
        #pragma unroll
        for (int h = 0; h < 3; h++) {
            if (logit[h] > -INFINITY) { wh[h] = expf(logit[h] - mx); s += wh[h]; }
        }
        float inv = 1.0f / s;
        wh[0] *= inv; wh[1] *= inv; wh[2] *= inv;
    }

    float accF[CH];
    #pragma unroll
    for (int c = 0; c < CH; c++) accF[c] = 0.f;
    #pragma unroll
    for (int h = 0; h < 3; h++) {
        if (wh[h] > 0.f) {
            #pragma unroll
            for (int t = 0; t < 4; t++) {
                const float cw = wh[h] * tw[h][t];
                const f16x8* p = (const f16x8*)(fHb + (size_t)ti[h][t] * 96);
                #pragma unroll
                for (int c8 = 0; c8 < 12; c8++) {
                    f16x8 vv = p[c8];
                    #pragma unroll
                    for (int e = 0; e < 8; e++)
                        accF[c8 * 8 + e] = fmaf(cw, (float)vv[e], accF[c8 * 8 + e]);
                }
            }
        }
    }
    _Float16* op = out + ((size_t)(b * PD + i + 1) * PD + (j + 1)) * CH;
    #pragma unroll
    for (int c8 = 0; c8 < 12; ++c8) {
        f16x8 v;
        #pragma unroll
        for (int k = 0; k < 8; ++k) v[k] = (_Float16)accF[c8 * 8 + k];
        *(f16x8*)(op + c8 * 8) = v;
    }
}

// ---------------------------------------------------------------------------
// Conv 3x3 + BN + ReLU, f16 MFMA implicit GEMM.
// Block: 8 rows x 32 cols, 4 waves; wave = 2 rows = 4 pixel-tiles x 6 oc-tiles
// (24 MFMA per K-step). A operand = WEIGHTS (oc on D's row dim), B = pixels
// from LDS halo tile. One-step register prefetch; no barriers after staging.
// Epilogue: lane holds 4 consecutive oc per pixel -> direct global stores.
// MODE 0: padded HWC f16 (8B f16x4 stores).  MODE 1: CHW fp32 (coalesced).
// ---------------------------------------------------------------------------
template<int MODE>
__global__ __launch_bounds__(256, 2) void k_conv_mfma(
        const _Float16* __restrict__ in, const _Float16* __restrict__ wt,
        const float* __restrict__ bng, const float* __restrict__ bnb,
        const float* __restrict__ bnm, const float* __restrict__ bnv,
        void* __restrict__ outv) {
    __shared__ _Float16 sA[10 * 34 * 104];   // 70,720 B
    const int tid = threadIdx.x;
    const int w = tid >> 6, lane = tid & 63, q = lane >> 4, n = lane & 15;
    const int x0 = blockIdx.x * 32, y0 = blockIdx.y * 8, b = blockIdx.z;
    const _Float16* inb = in + (size_t)b * PPIX * CH;

    // stage halo tile: 10 rows x 34 cols x 96 ch, pixel stride 104 f16
    for (int idx = tid; idx < 10 * 34 * 12; idx += 256) {
        int pix = idx / 12, c8 = idx - pix * 12;
        int rr = pix / 34, cc = pix - rr * 34;
        *(f16x8*)(&sA[pix * 104 + c8 * 8]) =
            *(const f16x8*)(inb + ((size_t)(y0 + rr) * PD + (x0 + cc)) * CH + c8 * 8);
    }
    __syncthreads();

    f32x4 acc[6][4];
    #pragma unroll
    for (int ot = 0; ot < 6; ot++)
        #pragma unroll
        for (int pt = 0; pt < 4; pt++) acc[ot][pt] = (f32x4){0.f, 0.f, 0.f, 0.f};

    const _Float16* wtb = wt + n * CH + q * 8;   // + tap*9216 + ot*1536 + kc*32

    f16x8 wf[6], pf[4];
    #pragma unroll
    for (int ot = 0; ot < 6; ot++) wf[ot] = *(const f16x8*)(wtb + ot * 1536);
    #pragma unroll
    for (int pt = 0; pt < 4; pt++)
        pf[pt] = *(const f16x8*)(&sA[((2 * w + (pt >> 1)) * 34 + (pt & 1) * 16 + n) * 104 + q * 8]);

    #pragma unroll
    for (int step = 0; step < 27; ++step) {
        f16x8 wn[6], pn[4];
        if (step + 1 < 27) {
            const int st2 = step + 1, tap2 = st2 / 3, kc2 = st2 % 3;
            const int r2 = tap2 / 3, s2 = tap2 % 3;
            #pragma unroll
            for (int ot = 0; ot < 6; ot++)
                wn[ot] = *(const f16x8*)(wtb + tap2 * 9216 + ot * 1536 + kc2 * 32);
            #pragma unroll
            for (int pt = 0; pt < 4; pt++)
                pn[pt] = *(const f16x8*)(&sA[((2 * w + (pt >> 1) + r2) * 34
                                              + (pt & 1) * 16 + s2 + n) * 104 + kc2 * 32 + q * 8]);
        }
        #pragma unroll
        for (int ot = 0; ot < 6; ot++)
            #pragma unroll
            for (int pt = 0; pt < 4; pt++)
                acc[ot][pt] = __builtin_amdgcn_mfma_f32_16x16x32_f16(
                                  wf[ot], pf[pt], acc[ot][pt], 0, 0, 0);
        if (step + 1 < 27) {
            #pragma unroll
            for (int ot = 0; ot < 6; ot++) wf[ot] = wn[ot];
            #pragma unroll
            for (int pt = 0; pt < 4; pt++) pf[pt] = pn[pt];
        }
    }

    // BN per (ot, rg): oc = ot*16 + q*4 + rg
    float scv[6][4], shv[6][4];
    #pragma unroll
    for (int ot = 0; ot < 6; ot++)
        #pragma unroll
        for (int rg = 0; rg < 4; rg++) {
            int oc = ot * 16 + q * 4 + rg;
            scv[ot][rg] = bng[oc] * rsqrtf(bnv[oc] + 1e-3f);
            shv[ot][rg] = fmaf(-bnm[oc], scv[ot][rg], bnb[oc]);
        }

    if (MODE == 0) {
        _Float16* outb = (_Float16*)outv + (size_t)b * PPIX * CH;
        #pragma unroll
        for (int pt = 0; pt < 4; pt++) {
            const int orow = y0 + 2 * w + (pt >> 1) + 1;
            const int ocol = x0 + (pt & 1) * 16 + n + 1;
            _Float16* op = outb + ((size_t)orow * PD + ocol) * CH + q * 4;
            #pragma unroll
            for (int ot = 0; ot < 6; ot++) {
                f16x4 pv;
                #pragma unroll
                for (int rg = 0; rg < 4; rg++)
                    pv[rg] = (_Float16)fmaxf(fmaf(acc[ot][pt][rg], scv[ot][rg], shv[ot][rg]), 0.f);
                *(f16x4*)(op + ot * 16) = pv;
            }
        }
    } else {
        float* outb = (float*)outv + (size_t)b * CH * NCELL;
        #pragma unroll
        for (int pt = 0; pt < 4; pt++) {
            const int prow = y0 + 2 * w + (pt >> 1);
            const int pcol = x0 + (pt & 1) * 16 + n;
            #pragma unroll
            for (int ot = 0; ot < 6; ot++)
                #pragma unroll
                for (int rg = 0; rg < 4; rg++) {
                    int oc = ot * 16 + q * 4 + rg;
                    outb[(size_t)oc * NCELL + prow * BEV + pcol] =
                        fmaxf(fmaf(acc[ot][pt][rg], scv[ot][rg], shv[ot][rg]), 0.f);
                }
        }
    }
}

// ---------------------------------------------------------------------------
extern "C" void kernel_launch(void* const* d_in, const int* in_sizes, int n_in,
                              void* d_out, int out_size, void* d_ws, size_t ws_size,
                              hipStream_t stream) {
    const float* feat = (const float*)d_in[0];
    const float* l2i  = (const float*)d_in[1];
    const float* he   = (const float*)d_in[2];
    const float* dw1  = (const float*)d_in[3];
    const float* db1  = (const float*)d_in[4];
    const float* dw2  = (const float*)d_in[5];
    const float* db2  = (const float*)d_in[6];
    const float* sw1  = (const float*)d_in[7];
    const float* sb1  = (const float*)d_in[8];
    const float* sw2  = (const float*)d_in[9];
    const float* sb2  = (const float*)d_in[10];
    const float* c1w  = (const float*)d_in[11];
    const float* bn1g = (const float*)d_in[12];
    const float* bn1b = (const float*)d_in[13];
    const float* bn1m = (const float*)d_in[14];
    const float* bn1v = (const float*)d_in[15];
    const float* c2w  = (const float*)d_in[16];
    const float* bn2g = (const float*)d_in[17];
    const float* bn2b = (const float*)d_in[18];
    const float* bn2m = (const float*)d_in[19];
    const float* bn2v = (const float*)d_in[20];

    float* ws = (float*)d_ws;
    _Float16*  bufB   = (_Float16*)(ws + OFF_BUFB);
    _Float16*  featS  = (_Float16*)(ws + OFF_FS);   // aliases bufB (dead before conv1)
    _Float16*  featH  = (_Float16*)(ws + OFF_FH);   // aliases bufB (dead before conv1)
    _Float16*  wtp    = (_Float16*)(ws + OFF_WT);
    float*     hW     = ws + OFF_HW;
    float*     baseT  = ws + OFF_BASE;
    _Float16*  bufA   = (_Float16*)(ws + OFF_BUFA);
    _Float16*  wt1    = wtp;
    _Float16*  wt2    = wtp + 82944;

    hipLaunchKernelGGL(k_precompute, dim3(1), dim3(256), 0, stream,
                       dw2, sw1, db2, he, sb1, hW, baseT);
    hipLaunchKernelGGL(k_wprep, dim3(648), dim3(256), 0, stream, c1w, c2w, wtp);
    hipLaunchKernelGGL(k_feats, dim3(FPIX / 64, 2), dim3(64), 0, stream,
                       feat, sw1, featS, featH);
    hipLaunchKernelGGL(k_border, dim3(11), dim3(256), 0, stream, bufA);
    hipLaunchKernelGGL(k_lift, dim3(NCELL / 128, 2), dim3(128), 0, stream,
                       featS, featH, l2i, dw1, db1, sw2, sb2, hW, baseT, bufA);
    // bufB borders only after k_lift (featS/featH alias bufB)
    hipLaunchKernelGGL(k_border, dim3(11), dim3(256), 0, stream, bufB);
    hipLaunchKernelGGL((k_conv_mfma<0>), dim3(10, 40, 2), dim3(256), 0, stream,
                       bufA, wt1, bn1g, bn1b, bn1m, bn1v, (void*)bufB);
    hipLaunchKernelGGL((k_conv_mfma<1>), dim3(10, 40, 2), dim3(256), 0, stream,
                       bufB, wt2, bn2g, bn2b, bn2m, bn2v, d_out);
}

// Round 5
// 397.779 us; speedup vs baseline: 1.7512x; 1.1424x over previous
//
#include <hip/hip_runtime.h>
#include <math.h>

typedef _Float16 f16x8 __attribute__((ext_vector_type(8)));
typedef _Float16 f16x4 __attribute__((ext_vector_type(4)));
typedef float    f32x4 __attribute__((ext_vector_type(4)));

#define FEAT_H 128
#define FEAT_W 352
#define FPIX   (FEAT_H * FEAT_W)   // 45056
#define BEV    320
#define NCELL  (BEV * BEV)         // 102400
#define CH     96
#define PD     322                 // padded spatial dim
#define PPIX   (PD * PD)           // 103684

// ---- workspace layout (float offsets) ----
// bufB f16 [2][PPIX][96] at 0. featS16/featH16 alias inside bufB (dead before
// conv1 writes bufB; k_border(bufB) runs only after k_lift).
#define N_PADF    (2 * PPIX * CH / 2)            // 9,953,664 floats
#define OFF_BUFB  0
#define OFF_FS    0                              // featS16: 2*45056*64 f16 = 2,883,584 fl
#define OFF_FH    2883584                        // featH16: 2*45056*96 f16 = 4,325,376 fl
#define OFF_WT    (N_PADF)                       // f16 2*9*96*96 = 82,944 floats
#define OFF_HW    (OFF_WT + 82944)               // 64*64 fp32
#define OFF_BASE  (OFF_HW + 4096)                // baseT 192 | wD 64 | flag 1 (512 total)
#define OFF_WD    (OFF_BASE + 192)
#define OFF_FLAG  (OFF_BASE + 256)
#define OFF_BUFA  (OFF_BASE + 512)               // f16 padded conv1 input

// ---------------------------------------------------------------------------
// hW = dw2 @ sw1 (64x64); base[h] = (db2 + he[h]) @ sw1 + sb1;
// wD[k] = sum_{j: dw1[j]>0} dw1[j]*hW[j][k];  flag = (db1 == 0) ? 1 : 0
// ---------------------------------------------------------------------------
__global__ void k_precompute(const float* __restrict__ dw2, const float* __restrict__ sw1,
                             const float* __restrict__ db2, const float* __restrict__ he,
                             const float* __restrict__ sb1, const float* __restrict__ dw1,
                             const float* __restrict__ db1,
                             float* __restrict__ hW, float* __restrict__ baseT,
                             float* __restrict__ wD, float* __restrict__ flagp) {
    const int t = threadIdx.x;
    for (int idx = t; idx < 64 * 64; idx += 256) {
        int j = idx >> 6, k = idx & 63;
        float s = 0.f;
        for (int c = 0; c < CH; c++) s = fmaf(dw2[j * CH + c], sw1[c * 64 + k], s);
        hW[idx] = s;
    }
    for (int idx = t; idx < 3 * 64; idx += 256) {
        int h = idx >> 6, k = idx & 63;
        float s = sb1[k];
        for (int c = 0; c < CH; c++) s = fmaf(db2[c] + he[h * CH + c], sw1[c * 64 + k], s);
        baseT[idx] = s;
    }
    __syncthreads();
    if (t < 64) {
        float s = 0.f;
        for (int j = 0; j < 64; j++) {
            float w = dw1[j];
            if (w > 0.f) s = fmaf(w, hW[j * 64 + t], s);
        }
        wD[t] = s;
    }
    if (t == 0) {
        float mx = 0.f;
        for (int j = 0; j < 64; j++) mx = fmaxf(mx, fabsf(db1[j]));
        flagp[0] = (mx == 0.f) ? 1.f : 0.f;
    }
}

// ---------------------------------------------------------------------------
// Weight prep: wt[cv][tap][oc][ic] (f16)  from  w[oc][ic][3][3] (fp32)
// ---------------------------------------------------------------------------
__global__ void k_wprep(const float* __restrict__ w1, const float* __restrict__ w2,
                        _Float16* __restrict__ wt) {
    int idx = blockIdx.x * 256 + threadIdx.x;       // 2*9*96*96 = 165888
    if (idx >= 165888) return;
    int cv = idx / 82944; int r = idx - cv * 82944;
    int tap = r / 9216;   int rr = r - tap * 9216;
    int oc = rr / 96;     int ic = rr - oc * 96;
    const float* src = cv ? w2 : w1;
    wt[idx] = (_Float16)src[(oc * 96 + ic) * 9 + tap];
}

// ---------------------------------------------------------------------------
// Zero the 1-pixel border of a padded f16 HWC buffer [2][322][322][96]
// ---------------------------------------------------------------------------
__global__ void k_border(_Float16* __restrict__ buf) {
    int idx = blockIdx.x * 256 + threadIdx.x;       // 2*1284 = 2568 border pixels
    if (idx >= 2568) return;
    int img = idx / 1284; int p = idx - img * 1284;
    int row, col;
    if (p < 322)      { row = 0;           col = p; }
    else if (p < 644) { row = 321;         col = p - 322; }
    else if (p < 964) { row = p - 644 + 1; col = 0; }
    else              { row = p - 964 + 1; col = 321; }
    _Float16* q = buf + ((size_t)(img * PD + row) * PD + col) * CH;
    f16x8 z = {};
    #pragma unroll
    for (int c8 = 0; c8 < 12; ++c8) *(f16x8*)(q + c8 * 8) = z;
}

// ---------------------------------------------------------------------------
// k_feats: featS16[b][pix][64] = f16(feat[b][:][pix] @ sw1)
//          featH16[b][pix][96] = f16(feat[b][:][pix])   (CHW -> HWC transpose)
// ---------------------------------------------------------------------------
__global__ __launch_bounds__(64) void k_feats(const float* __restrict__ feat,
                                              const float* __restrict__ sw1,
                                              _Float16* __restrict__ featS,
                                              _Float16* __restrict__ featH) {
    const int t = threadIdx.x;
    const int pb = blockIdx.x * 64;
    const int b = blockIdx.y;
    __shared__ float ld[CH * 64];
    const float* fp = feat + (size_t)b * CH * FPIX + pb;
    #pragma unroll 8
    for (int c = 0; c < CH; c++) ld[c * 64 + t] = fp[(size_t)c * FPIX + t];
    __syncthreads();

    float acc[64];
    #pragma unroll
    for (int k = 0; k < 64; k++) acc[k] = 0.f;
    for (int c = 0; c < CH; c++) {
        float x = ld[c * 64 + t];
        const float4* wr = (const float4*)(sw1 + c * 64);
        #pragma unroll
        for (int k4 = 0; k4 < 16; k4++) {
            float4 w = wr[k4];
            acc[4 * k4 + 0] = fmaf(x, w.x, acc[4 * k4 + 0]);
            acc[4 * k4 + 1] = fmaf(x, w.y, acc[4 * k4 + 1]);
            acc[4 * k4 + 2] = fmaf(x, w.z, acc[4 * k4 + 2]);
            acc[4 * k4 + 3] = fmaf(x, w.w, acc[4 * k4 + 3]);
        }
    }
    _Float16* opS = featS + ((size_t)b * FPIX + pb + t) * 64;
    #pragma unroll
    for (int k8 = 0; k8 < 8; k8++) {
        f16x8 v;
        #pragma unroll
        for (int e = 0; e < 8; e++) v[e] = (_Float16)acc[k8 * 8 + e];
        *(f16x8*)(opS + k8 * 8) = v;
    }
    _Float16* opH = featH + ((size_t)b * FPIX + pb + t) * 96;
    #pragma unroll
    for (int c8 = 0; c8 < 12; c8++) {
        f16x8 v;
        #pragma unroll
        for (int e = 0; e < 8; e++) v[e] = (_Float16)ld[(c8 * 8 + e) * 64 + t];
        *(f16x8*)(opH + c8 * 8) = v;
    }
}

// ---------------------------------------------------------------------------
// Lift v2: 384 threads = 128 cells x 3 heights (height wave-uniform).
// Score-MLP hidden evaluated in 16-wide chunks; depth-MLP term is d*wD
// (exact when db1==0, runtime-checked; chunked matvec fallback otherwise).
// Softmax via LDS; weighted 96-ch gather accumulated in LDS (stride 97).
// ---------------------------------------------------------------------------
__global__ __launch_bounds__(384, 4) void k_lift(const _Float16* __restrict__ featS,
                                                 const _Float16* __restrict__ featH,
                                                 const float* __restrict__ l2i,
                                                 const float* __restrict__ dw1,
                                                 const float* __restrict__ db1,
                                                 const float* __restrict__ sw2,
                                                 const float* __restrict__ sb2,
                                                 const float* __restrict__ hW,
                                                 const float* __restrict__ baseT,
                                                 const float* __restrict__ wD,
                                                 const float* __restrict__ flagp,
                                                 _Float16* __restrict__ out) {
    __shared__ float slog[3][128];
    __shared__ float sacc[128][97];
    const int tid = threadIdx.x;
    const int h = tid >> 7;          // wave-uniform
    const int c = tid & 127;
    const int b = blockIdx.y;
    const int n = blockIdx.x * 128 + c;
    const int i = n / BEV, j = n % BEV;
    const float px = ((j + 0.5f) / 320.0f) * 102.4f - 51.2f;
    const float py = ((i + 0.5f) / 320.0f) * 102.4f - 51.2f;
    const float* M = l2i + b * 16;
    const float m00 = M[0], m01 = M[1], m02 = M[2], m03 = M[3];
    const float m10 = M[4], m11 = M[5], m12 = M[6], m13 = M[7];
    const float m20 = M[8], m21 = M[9], m22 = M[10], m23 = M[11];

    const _Float16* fSb = featS + (size_t)b * FPIX * 64;
    const _Float16* fHb = featH + (size_t)b * FPIX * 96;

    const float z = (float)h;
    const float p0 = m03 + m00 * px + m01 * py + m02 * z;
    const float p1 = m13 + m10 * px + m11 * py + m12 * z;
    const float dep = m23 + m20 * px + m21 * py + m22 * z;
    const float dv = fmaxf(dep, 1e-5f);
    const float u = p0 / dv, v = p1 / dv;
    const float gx = (u / 351.0f) * 2.0f - 1.0f;
    const float gy = (v / 127.0f) * 2.0f - 1.0f;
    const bool valid = (dep > 1e-3f) && (fabsf(gx) <= 1.0f) && (fabsf(gy) <= 1.0f);

    int   ti0 = 0, ti1 = 0, ti2 = 0, ti3 = 0;
    float tw0 = 0.f, tw1 = 0.f, tw2 = 0.f, tw3 = 0.f;
    float lg = -INFINITY;

    if (valid) {
        float xs = (gx + 1.0f) * 0.5f * 351.0f;
        float ys = (gy + 1.0f) * 0.5f * 127.0f;
        float xf = floorf(xs), yf = floorf(ys);
        int x0 = (int)xf, y0 = (int)yf;
        float wx = xs - xf, wy = ys - yf;
        int x1 = (x0 < FEAT_W - 1) ? x0 + 1 : x0;
        int y1 = (y0 < FEAT_H - 1) ? y0 + 1 : y0;
        ti0 = y0 * FEAT_W + x0;  ti1 = y0 * FEAT_W + x1;
        ti2 = y1 * FEAT_W + x0;  ti3 = y1 * FEAT_W + x1;
        tw0 = (1.f - wx) * (1.f - wy);  tw1 = wx * (1.f - wy);
        tw2 = (1.f - wx) * wy;          tw3 = wx * wy;

        const float dl = log1pf(fmaxf(dep, 1e-3f));
        const _Float16* q0 = fSb + (size_t)ti0 * 64;
        const _Float16* q1 = fSb + (size_t)ti1 * 64;
        const _Float16* q2 = fSb + (size_t)ti2 * 64;
        const _Float16* q3 = fSb + (size_t)ti3 * 64;
        lg = sb2[0];
        const bool fast = (flagp[0] != 0.f);
        if (fast) {
            #pragma unroll
            for (int kc = 0; kc < 4; kc++) {
                float hid[16];
                const float4* bs = (const float4*)(baseT + h * 64 + kc * 16);
                const float4* wd = (const float4*)(wD + kc * 16);
                #pragma unroll
                for (int q4 = 0; q4 < 4; q4++) {
                    float4 bv = bs[q4], wv = wd[q4];
                    hid[4 * q4 + 0] = fmaf(dl, wv.x, bv.x);
                    hid[4 * q4 + 1] = fmaf(dl, wv.y, bv.y);
                    hid[4 * q4 + 2] = fmaf(dl, wv.z, bv.z);
                    hid[4 * q4 + 3] = fmaf(dl, wv.w, bv.w);
                }
                f16x8 a0 = *(const f16x8*)(q0 + kc * 16),  a0b = *(const f16x8*)(q0 + kc * 16 + 8);
                f16x8 a1 = *(const f16x8*)(q1 + kc * 16),  a1b = *(const f16x8*)(q1 + kc * 16 + 8);
                f16x8 a2 = *(const f16x8*)(q2 + kc * 16),  a2b = *(const f16x8*)(q2 + kc * 16 + 8);
                f16x8 a3 = *(const f16x8*)(q3 + kc * 16),  a3b = *(const f16x8*)(q3 + kc * 16 + 8);
                #pragma unroll
                for (int e = 0; e < 8; e++) {
                    hid[e]     = fmaf(tw0, (float)a0[e],  fmaf(tw1, (float)a1[e],
                                 fmaf(tw2, (float)a2[e],  fmaf(tw3, (float)a3[e],  hid[e]))));
                    hid[e + 8] = fmaf(tw0, (float)a0b[e], fmaf(tw1, (float)a1b[e],
                                 fmaf(tw2, (float)a2b[e], fmaf(tw3, (float)a3b[e], hid[e + 8]))));
                }
                const float4* s2 = (const float4*)(sw2 + kc * 16);
                #pragma unroll
                for (int q4 = 0; q4 < 4; q4++) {
                    float4 sv = s2[q4];
                    lg = fmaf(fmaxf(hid[4 * q4 + 0], 0.f), sv.x, lg);
                    lg = fmaf(fmaxf(hid[4 * q4 + 1], 0.f), sv.y, lg);
                    lg = fmaf(fmaxf(hid[4 * q4 + 2], 0.f), sv.z, lg);
                    lg = fmaf(fmaxf(hid[4 * q4 + 3], 0.f), sv.w, lg);
                }
            }
        } else {
            // general fallback (db1 != 0): chunked 64x64 matvec
            #pragma unroll
            for (int kc = 0; kc < 4; kc++) {
                float hid[16];
                const float4* bs = (const float4*)(baseT + h * 64 + kc * 16);
                #pragma unroll
                for (int q4 = 0; q4 < 4; q4++) {
                    float4 bv = bs[q4];
                    hid[4 * q4 + 0] = bv.x; hid[4 * q4 + 1] = bv.y;
                    hid[4 * q4 + 2] = bv.z; hid[4 * q4 + 3] = bv.w;
                }
                f16x8 a0 = *(const f16x8*)(q0 + kc * 16),  a0b = *(const f16x8*)(q0 + kc * 16 + 8);
                f16x8 a1 = *(const f16x8*)(q1 + kc * 16),  a1b = *(const f16x8*)(q1 + kc * 16 + 8);
                f16x8 a2 = *(const f16x8*)(q2 + kc * 16),  a2b = *(const f16x8*)(q2 + kc * 16 + 8);
                f16x8 a3 = *(const f16x8*)(q3 + kc * 16),  a3b = *(const f16x8*)(q3 + kc * 16 + 8);
                #pragma unroll
                for (int e = 0; e < 8; e++) {
                    hid[e]     = fmaf(tw0, (float)a0[e],  fmaf(tw1, (float)a1[e],
                                 fmaf(tw2, (float)a2[e],  fmaf(tw3, (float)a3[e],  hid[e]))));
                    hid[e + 8] = fmaf(tw0, (float)a0b[e], fmaf(tw1, (float)a1b[e],
                                 fmaf(tw2, (float)a2b[e], fmaf(tw3, (float)a3b[e], hid[e + 8]))));
                }
                for (int jj = 0; jj < 64; jj++) {
                    float hd = fmaxf(fmaf(dl, dw1[jj], db1[jj]), 0.f);
                    const float4* hr = (const float4*)(hW + jj * 64 + kc * 16);
                    #pragma unroll
                    for (int q4 = 0; q4 < 4; q4++) {
                        float4 wv = hr[q4];
                        hid[4 * q4 + 0] = fmaf(hd, wv.x, hid[4 * q4 + 0]);
                        hid[4 * q4 + 1] = fmaf(hd, wv.y, hid[4 * q4 + 1]);
                        hid[4 * q4 + 2] = fmaf(hd, wv.z, hid[4 * q4 + 2]);
                        hid[4 * q4 + 3] = fmaf(hd, wv.w, hid[4 * q4 + 3]);
                    }
                }
                const float4* s2 = (const float4*)(sw2 + kc * 16);
                #pragma unroll
                for (int q4 = 0; q4 < 4; q4++) {
                    float4 sv = s2[q4];
                    lg = fmaf(fmaxf(hid[4 * q4 + 0], 0.f), sv.x, lg);
                    lg = fmaf(fmaxf(hid[4 * q4 + 1], 0.f), sv.y, lg);
                    lg = fmaf(fmaxf(hid[4 * q4 + 2], 0.f), sv.z, lg);
                    lg = fmaf(fmaxf(hid[4 * q4 + 3], 0.f), sv.w, lg);
                }
            }
        }
    }

    slog[h][c] = lg;
    __syncthreads();
    const float l0 = slog[0][c], l1 = slog[1][c], l2v = slog[2][c];
    const float mx = fmaxf(l0, fmaxf(l1, l2v));
    float myw = 0.f;
    if (mx > -INFINITY) {
        float e0 = (l0 > -INFINITY) ? expf(l0 - mx) : 0.f;
        float e1 = (l1 > -INFINITY) ? expf(l1 - mx) : 0.f;
        float e2 = (l2v > -INFINITY) ? expf(l2v - mx) : 0.f;
        float s = e0 + e1 + e2;
        float me = (h == 0) ? e0 : (h == 1) ? e1 : e2;
        myw = me / s;
    }

    const float cw0 = myw * tw0, cw1 = myw * tw1, cw2 = myw * tw2, cw3 = myw * tw3;
    const _Float16* g0 = fHb + (size_t)ti0 * 96;
    const _Float16* g1 = fHb + (size_t)ti1 * 96;
    const _Float16* g2 = fHb + (size_t)ti2 * 96;
    const _Float16* g3 = fHb + (size_t)ti3 * 96;
    float* srow = &sacc[c][0];

    if (h == 0) {
        if (myw > 0.f) {
            #pragma unroll
            for (int c8 = 0; c8 < 12; c8++) {
                f16x8 v0 = *(const f16x8*)(g0 + c8 * 8);
                f16x8 v1 = *(const f16x8*)(g1 + c8 * 8);
                f16x8 v2 = *(const f16x8*)(g2 + c8 * 8);
                f16x8 v3 = *(const f16x8*)(g3 + c8 * 8);
                #pragma unroll
                for (int e = 0; e < 8; e++)
                    srow[c8 * 8 + e] = fmaf(cw0, (float)v0[e], fmaf(cw1, (float)v1[e],
                                       fmaf(cw2, (float)v2[e], cw3 * (float)v3[e])));
            }
        } else {
            #pragma unroll
            for (int k = 0; k < 96; k++) srow[k] = 0.f;
        }
    }
    __syncthreads();
    if (h == 1 && myw > 0.f) {
        #pragma unroll
        for (int c8 = 0; c8 < 12; c8++) {
            f16x8 v0 = *(const f16x8*)(g0 + c8 * 8);
            f16x8 v1 = *(const f16x8*)(g1 + c8 * 8);
            f16x8 v2 = *(const f16x8*)(g2 + c8 * 8);
            f16x8 v3 = *(const f16x8*)(g3 + c8 * 8);
            #pragma unroll
            for (int e = 0; e < 8; e++)
                srow[c8 * 8 + e] += fmaf(cw0, (float)v0[e], fmaf(cw1, (float)v1[e],
                                    fmaf(cw2, (float)v2[e], cw3 * (float)v3[e])));
        }
    }
    __syncthreads();
    if (h == 2 && myw > 0.f) {
        #pragma unroll
        for (int c8 = 0; c8 < 12; c8++) {
            f16x8 v0 = *(const f16x8*)(g0 + c8 * 8);
            f16x8 v1 = *(const f16x8*)(g1 + c8 * 8);
            f16x8 v2 = *(const f16x8*)(g2 + c8 * 8);
            f16x8 v3 = *(const f16x8*)(g3 + c8 * 8);
            #pragma unroll
            for (int e = 0; e < 8; e++)
                srow[c8 * 8 + e] += fmaf(cw0, (float)v0[e], fmaf(cw1, (float)v1[e],
                                    fmaf(cw2, (float)v2[e], cw3 * (float)v3[e])));
        }
    }
    __syncthreads();

    if (h == 0) {
        _Float16* op = out + ((size_t)(b * PD + i + 1) * PD + (j + 1)) * CH;
        #pragma unroll
        for (int c8 = 0; c8 < 12; ++c8) {
            f16x8 v;
            #pragma unroll
            for (int e = 0; e < 8; ++e) v[e] = (_Float16)srow[c8 * 8 + e];
            *(f16x8*)(op + c8 * 8) = v;
        }
    }
}

// ---------------------------------------------------------------------------
// Conv 3x3 + BN + ReLU, f16 MFMA implicit GEMM.
// Block: 8 rows x 32 cols, 4 waves; wave = 2 rows = 4 pixel-tiles x 6 oc-tiles
// (24 MFMA per K-step). A operand = WEIGHTS (oc on D's row dim), B = pixels
// from LDS halo tile. One-step register prefetch; no barriers after staging.
// MODE 0: padded HWC f16 (8B f16x4 stores).  MODE 1: CHW fp32 (coalesced).
// ---------------------------------------------------------------------------
template<int MODE>
__global__ __launch_bounds__(256, 2) void k_conv_mfma(
        const _Float16* __restrict__ in, const _Float16* __restrict__ wt,
        const float* __restrict__ bng, const float* __restrict__ bnb,
        const float* __restrict__ bnm, const float* __restrict__ bnv,
        void* __restrict__ outv) {
    __shared__ _Float16 sA[10 * 34 * 104];   // 70,720 B
    const int tid = threadIdx.x;
    const int w = tid >> 6, lane = tid & 63, q = lane >> 4, n = lane & 15;
    const int x0 = blockIdx.x * 32, y0 = blockIdx.y * 8, b = blockIdx.z;
    const _Float16* inb = in + (size_t)b * PPIX * CH;

    for (int idx = tid; idx < 10 * 34 * 12; idx += 256) {
        int pix = idx / 12, c8 = idx - pix * 12;
        int rr = pix / 34, cc = pix - rr * 34;
        *(f16x8*)(&sA[pix * 104 + c8 * 8]) =
            *(const f16x8*)(inb + ((size_t)(y0 + rr) * PD + (x0 + cc)) * CH + c8 * 8);
    }
    __syncthreads();

    f32x4 acc[6][4];
    #pragma unroll
    for (int ot = 0; ot < 6; ot++)
        #pragma unroll
        for (int pt = 0; pt < 4; pt++) acc[ot][pt] = (f32x4){0.f, 0.f, 0.f, 0.f};

    const _Float16* wtb = wt + n * CH + q * 8;   // + tap*9216 + ot*1536 + kc*32

    f16x8 wf[6], pf[4];
    #pragma unroll
    for (int ot = 0; ot < 6; ot++) wf[ot] = *(const f16x8*)(wtb + ot * 1536);
    #pragma unroll
    for (int pt = 0; pt < 4; pt++)
        pf[pt] = *(const f16x8*)(&sA[((2 * w + (pt >> 1)) * 34 + (pt & 1) * 16 + n) * 104 + q * 8]);

    #pragma unroll
    for (int step = 0; step < 27; ++step) {
        f16x8 wn[6], pn[4];
        if (step + 1 < 27) {
            const int st2 = step + 1, tap2 = st2 / 3, kc2 = st2 % 3;
            const int r2 = tap2 / 3, s2 = tap2 % 3;
            #pragma unroll
            for (int ot = 0; ot < 6; ot++)
                wn[ot] = *(const f16x8*)(wtb + tap2 * 9216 + ot * 1536 + kc2 * 32);
            #pragma unroll
            for (int pt = 0; pt < 4; pt++)
                pn[pt] = *(const f16x8*)(&sA[((2 * w + (pt >> 1) + r2) * 34
                                              + (pt & 1) * 16 + s2 + n) * 104 + kc2 * 32 + q * 8]);
        }
        #pragma unroll
        for (int ot = 0; ot < 6; ot++)
            #pragma unroll
            for (int pt = 0; pt < 4; pt++)
                acc[ot][pt] = __builtin_amdgcn_mfma_f32_16x16x32_f16(
                                  wf[ot], pf[pt], acc[ot][pt], 0, 0, 0);
        if (step + 1 < 27) {
            #pragma unroll
            for (int ot = 0; ot < 6; ot++) wf[ot] = wn[ot];
            #pragma unroll
            for (int pt = 0; pt < 4; pt++) pf[pt] = pn[pt];
        }
    }

    float scv[6][4], shv[6][4];
    #pragma unroll
    for (int ot = 0; ot < 6; ot++)
        #pragma unroll
        for (int rg = 0; rg < 4; rg++) {
            int oc = ot * 16 + q * 4 + rg;
            scv[ot][rg] = bng[oc] * rsqrtf(bnv[oc] + 1e-3f);
            shv[ot][rg] = fmaf(-bnm[oc], scv[ot][rg], bnb[oc]);
        }

    if (MODE == 0) {
        _Float16* outb = (_Float16*)outv + (size_t)b * PPIX * CH;
        #pragma unroll
        for (int pt = 0; pt < 4; pt++) {
            const int orow = y0 + 2 * w + (pt >> 1) + 1;
            const int ocol = x0 + (pt & 1) * 16 + n + 1;
            _Float16* op = outb + ((size_t)orow * PD + ocol) * CH + q * 4;
            #pragma unroll
            for (int ot = 0; ot < 6; ot++) {
                f16x4 pv;
                #pragma unroll
                for (int rg = 0; rg < 4; rg++)
                    pv[rg] = (_Float16)fmaxf(fmaf(acc[ot][pt][rg], scv[ot][rg], shv[ot][rg]), 0.f);
                *(f16x4*)(op + ot * 16) = pv;
            }
        }
    } else {
        float* outb = (float*)outv + (size_t)b * CH * NCELL;
        #pragma unroll
        for (int pt = 0; pt < 4; pt++) {
            const int prow = y0 + 2 * w + (pt >> 1);
            const int pcol = x0 + (pt & 1) * 16 + n;
            #pragma unroll
            for (int ot = 0; ot < 6; ot++)
                #pragma unroll
                for (int rg = 0; rg < 4; rg++) {
                    int oc = ot * 16 + q * 4 + rg;
                    outb[(size_t)oc * NCELL + prow * BEV + pcol] =
                        fmaxf(fmaf(acc[ot][pt][rg], scv[ot][rg], shv[ot][rg]), 0.f);
                }
        }
    }
}

// ---------------------------------------------------------------------------
extern "C" void kernel_launch(void* const* d_in, const int* in_sizes, int n_in,
                              void* d_out, int out_size, void* d_ws, size_t ws_size,
                              hipStream_t stream) {
    const float* feat = (const float*)d_in[0];
    const float* l2i  = (const float*)d_in[1];
    const float* he   = (const float*)d_in[2];
    const float* dw1  = (const float*)d_in[3];
    const float* db1  = (const float*)d_in[4];
    const float* dw2  = (const float*)d_in[5];
    const float* db2  = (const float*)d_in[6];
    const float* sw1  = (const float*)d_in[7];
    const float* sb1  = (const float*)d_in[8];
    const float* sw2  = (const float*)d_in[9];
    const float* sb2  = (const float*)d_in[10];
    const float* c1w  = (const float*)d_in[11];
    const float* bn1g = (const float*)d_in[12];
    const float* bn1b = (const float*)d_in[13];
    const float* bn1m = (const float*)d_in[14];
    const float* bn1v = (const float*)d_in[15];
    const float* c2w  = (const float*)d_in[16];
    const float* bn2g = (const float*)d_in[17];
    const float* bn2b = (const float*)d_in[18];
    const float* bn2m = (const float*)d_in[19];
    const float* bn2v = (const float*)d_in[20];

    float* ws = (float*)d_ws;
    _Float16*  bufB   = (_Float16*)(ws + OFF_BUFB);
    _Float16*  featS  = (_Float16*)(ws + OFF_FS);   // aliases bufB (dead before conv1)
    _Float16*  featH  = (_Float16*)(ws + OFF_FH);   // aliases bufB (dead before conv1)
    _Float16*  wtp    = (_Float16*)(ws + OFF_WT);
    float*     hW     = ws + OFF_HW;
    float*     baseT  = ws + OFF_BASE;
    float*     wD     = ws + OFF_WD;
    float*     flagp  = ws + OFF_FLAG;
    _Float16*  bufA   = (_Float16*)(ws + OFF_BUFA);
    _Float16*  wt1    = wtp;
    _Float16*  wt2    = wtp + 82944;

    hipLaunchKernelGGL(k_precompute, dim3(1), dim3(256), 0, stream,
                       dw2, sw1, db2, he, sb1, dw1, db1, hW, baseT, wD, flagp);
    hipLaunchKernelGGL(k_wprep, dim3(648), dim3(256), 0, stream, c1w, c2w, wtp);
    hipLaunchKernelGGL(k_feats, dim3(FPIX / 64, 2), dim3(64), 0, stream,
                       feat, sw1, featS, featH);
    hipLaunchKernelGGL(k_border, dim3(11), dim3(256), 0, stream, bufA);
    hipLaunchKernelGGL(k_lift, dim3(NCELL / 128, 2), dim3(384), 0, stream,
                       featS, featH, l2i, dw1, db1, sw2, sb2, hW, baseT, wD, flagp, bufA);
    // bufB borders only after k_lift (featS/featH alias bufB)
    hipLaunchKernelGGL(k_border, dim3(11), dim3(256), 0, stream, bufB);
    hipLaunchKernelGGL((k_conv_mfma<0>), dim3(10, 40, 2), dim3(256), 0, stream,
                       bufA, wt1, bn1g, bn1b, bn1m, bn1v, (void*)bufB);
    hipLaunchKernelGGL((k_conv_mfma<1>), dim3(10, 40, 2), dim3(256), 0, stream,
                       bufB, wt2, bn2g, bn2b, bn2m, bn2v, d_out);
}

// Round 6
// 382.129 us; speedup vs baseline: 1.8229x; 1.0410x over previous
//
#include <hip/hip_runtime.h>
#include <math.h>

typedef _Float16 f16x8 __attribute__((ext_vector_type(8)));
typedef _Float16 f16x4 __attribute__((ext_vector_type(4)));
typedef float    f32x4 __attribute__((ext_vector_type(4)));

#define FEAT_H 128
#define FEAT_W 352
#define FPIX   (FEAT_H * FEAT_W)   // 45056
#define BEV    320
#define NCELL  (BEV * BEV)         // 102400
#define CH     96
#define PD     322                 // padded spatial dim
#define PPIX   (PD * PD)           // 103684

// ---- workspace layout (float offsets) ----
#define N_PADF    (2 * PPIX * CH / 2)            // 9,953,664 floats
#define OFF_BUFB  0
#define OFF_FS    0                              // featS16: 2*45056*64 f16
#define OFF_FH    2883584                        // featH16: 2*45056*96 f16
#define OFF_WT    (N_PADF)                       // f16 2*9*96*96 = 82,944 floats
#define OFF_HW    (OFF_WT + 82944)               // 64*64 fp32
#define OFF_BASE  (OFF_HW + 4096)                // baseT 192 | wD 64 | flag 1
#define OFF_WD    (OFF_BASE + 192)
#define OFF_FLAG  (OFF_BASE + 256)
#define OFF_BUFA  (OFF_BASE + 512)               // f16 padded conv1 input

// ---------------------------------------------------------------------------
// k_setup: block 0 -> precompute (hW, baseT, wD, flag);
//          blocks 1..648 -> weight prep; blocks 649..659 -> bufA border zero.
// ---------------------------------------------------------------------------
__global__ void k_setup(const float* __restrict__ dw2, const float* __restrict__ sw1,
                        const float* __restrict__ db2, const float* __restrict__ he,
                        const float* __restrict__ sb1, const float* __restrict__ dw1,
                        const float* __restrict__ db1,
                        const float* __restrict__ w1, const float* __restrict__ w2,
                        float* __restrict__ hW, float* __restrict__ baseT,
                        float* __restrict__ wD, float* __restrict__ flagp,
                        _Float16* __restrict__ wt, _Float16* __restrict__ bufA) {
    const int bid = blockIdx.x;
    const int t = threadIdx.x;
    if (bid == 0) {
        for (int idx = t; idx < 64 * 64; idx += 256) {
            int j = idx >> 6, k = idx & 63;
            float s = 0.f;
            for (int c = 0; c < CH; c++) s = fmaf(dw2[j * CH + c], sw1[c * 64 + k], s);
            hW[idx] = s;
        }
        for (int idx = t; idx < 3 * 64; idx += 256) {
            int h = idx >> 6, k = idx & 63;
            float s = sb1[k];
            for (int c = 0; c < CH; c++) s = fmaf(db2[c] + he[h * CH + c], sw1[c * 64 + k], s);
            baseT[idx] = s;
        }
        __syncthreads();
        if (t < 64) {
            float s = 0.f;
            for (int j = 0; j < 64; j++) {
                float w = dw1[j];
                if (w > 0.f) s = fmaf(w, hW[j * 64 + t], s);
            }
            wD[t] = s;
        }
        if (t == 0) {
            float mx = 0.f;
            for (int j = 0; j < 64; j++) mx = fmaxf(mx, fabsf(db1[j]));
            flagp[0] = (mx == 0.f) ? 1.f : 0.f;
        }
    } else if (bid <= 648) {
        int idx = (bid - 1) * 256 + t;              // 0 .. 165887
        int cv = idx / 82944; int r = idx - cv * 82944;
        int tap = r / 9216;   int rr = r - tap * 9216;
        int oc = rr / 96;     int ic = rr - oc * 96;
        const float* src = cv ? w2 : w1;
        wt[idx] = (_Float16)src[(oc * 96 + ic) * 9 + tap];
    } else {
        int idx = (bid - 649) * 256 + t;            // 0 .. 2815 (need 2568)
        if (idx >= 2568) return;
        int img = idx / 1284; int p = idx - img * 1284;
        int row, col;
        if (p < 322)      { row = 0;           col = p; }
        else if (p < 644) { row = 321;         col = p - 322; }
        else if (p < 964) { row = p - 644 + 1; col = 0; }
        else              { row = p - 964 + 1; col = 321; }
        _Float16* q = bufA + ((size_t)(img * PD + row) * PD + col) * CH;
        f16x8 z = {};
        #pragma unroll
        for (int c8 = 0; c8 < 12; ++c8) *(f16x8*)(q + c8 * 8) = z;
    }
}

// ---------------------------------------------------------------------------
// Zero the 1-pixel border of a padded f16 HWC buffer [2][322][322][96]
// ---------------------------------------------------------------------------
__global__ void k_border(_Float16* __restrict__ buf) {
    int idx = blockIdx.x * 256 + threadIdx.x;       // 2*1284 = 2568 border pixels
    if (idx >= 2568) return;
    int img = idx / 1284; int p = idx - img * 1284;
    int row, col;
    if (p < 322)      { row = 0;           col = p; }
    else if (p < 644) { row = 321;         col = p - 322; }
    else if (p < 964) { row = p - 644 + 1; col = 0; }
    else              { row = p - 964 + 1; col = 321; }
    _Float16* q = buf + ((size_t)(img * PD + row) * PD + col) * CH;
    f16x8 z = {};
    #pragma unroll
    for (int c8 = 0; c8 < 12; ++c8) *(f16x8*)(q + c8 * 8) = z;
}

// ---------------------------------------------------------------------------
// k_feats: featS16[b][pix][64] = f16(feat[b][:][pix] @ sw1)
//          featH16[b][pix][96] = f16(feat[b][:][pix])   (CHW -> HWC transpose)
// ---------------------------------------------------------------------------
__global__ __launch_bounds__(64) void k_feats(const float* __restrict__ feat,
                                              const float* __restrict__ sw1,
                                              _Float16* __restrict__ featS,
                                              _Float16* __restrict__ featH) {
    const int t = threadIdx.x;
    const int pb = blockIdx.x * 64;
    const int b = blockIdx.y;
    __shared__ float ld[CH * 64];
    const float* fp = feat + (size_t)b * CH * FPIX + pb;
    #pragma unroll 8
    for (int c = 0; c < CH; c++) ld[c * 64 + t] = fp[(size_t)c * FPIX + t];
    __syncthreads();

    float acc[64];
    #pragma unroll
    for (int k = 0; k < 64; k++) acc[k] = 0.f;
    for (int c = 0; c < CH; c++) {
        float x = ld[c * 64 + t];
        const float4* wr = (const float4*)(sw1 + c * 64);
        #pragma unroll
        for (int k4 = 0; k4 < 16; k4++) {
            float4 w = wr[k4];
            acc[4 * k4 + 0] = fmaf(x, w.x, acc[4 * k4 + 0]);
            acc[4 * k4 + 1] = fmaf(x, w.y, acc[4 * k4 + 1]);
            acc[4 * k4 + 2] = fmaf(x, w.z, acc[4 * k4 + 2]);
            acc[4 * k4 + 3] = fmaf(x, w.w, acc[4 * k4 + 3]);
        }
    }
    _Float16* opS = featS + ((size_t)b * FPIX + pb + t) * 64;
    #pragma unroll
    for (int k8 = 0; k8 < 8; k8++) {
        f16x8 v;
        #pragma unroll
        for (int e = 0; e < 8; e++) v[e] = (_Float16)acc[k8 * 8 + e];
        *(f16x8*)(opS + k8 * 8) = v;
    }
    _Float16* opH = featH + ((size_t)b * FPIX + pb + t) * 96;
    #pragma unroll
    for (int c8 = 0; c8 < 12; c8++) {
        f16x8 v;
        #pragma unroll
        for (int e = 0; e < 8; e++) v[e] = (_Float16)ld[(c8 * 8 + e) * 64 + t];
        *(f16x8*)(opH + c8 * 8) = v;
    }
}

// ---------------------------------------------------------------------------
// Lift: 384 threads = 128 cells x 3 heights (height wave-uniform).
// ---------------------------------------------------------------------------
__global__ __launch_bounds__(384, 4) void k_lift(const _Float16* __restrict__ featS,
                                                 const _Float16* __restrict__ featH,
                                                 const float* __restrict__ l2i,
                                                 const float* __restrict__ dw1,
                                                 const float* __restrict__ db1,
                                                 const float* __restrict__ sw2,
                                                 const float* __restrict__ sb2,
                                                 const float* __restrict__ hW,
                                                 const float* __restrict__ baseT,
                                                 const float* __restrict__ wD,
                                                 const float* __restrict__ flagp,
                                                 _Float16* __restrict__ out) {
    __shared__ float slog[3][128];
    __shared__ float sacc[128][97];
    const int tid = threadIdx.x;
    const int h = tid >> 7;          // wave-uniform
    const int c = tid & 127;
    const int b = blockIdx.y;
    const int n = blockIdx.x * 128 + c;
    const int i = n / BEV, j = n % BEV;
    const float px = ((j + 0.5f) / 320.0f) * 102.4f - 51.2f;
    const float py = ((i + 0.5f) / 320.0f) * 102.4f - 51.2f;
    const float* M = l2i + b * 16;
    const float m00 = M[0], m01 = M[1], m02 = M[2], m03 = M[3];
    const float m10 = M[4], m11 = M[5], m12 = M[6], m13 = M[7];
    const float m20 = M[8], m21 = M[9], m22 = M[10], m23 = M[11];

    const _Float16* fSb = featS + (size_t)b * FPIX * 64;
    const _Float16* fHb = featH + (size_t)b * FPIX * 96;

    const float z = (float)h;
    const float p0 = m03 + m00 * px + m01 * py + m02 * z;
    const float p1 = m13 + m10 * px + m11 * py + m12 * z;
    const float dep = m23 + m20 * px + m21 * py + m22 * z;
    const float dv = fmaxf(dep, 1e-5f);
    const float u = p0 / dv, v = p1 / dv;
    const float gx = (u / 351.0f) * 2.0f - 1.0f;
    const float gy = (v / 127.0f) * 2.0f - 1.0f;
    const bool valid = (dep > 1e-3f) && (fabsf(gx) <= 1.0f) && (fabsf(gy) <= 1.0f);

    int   ti0 = 0, ti1 = 0, ti2 = 0, ti3 = 0;
    float tw0 = 0.f, tw1 = 0.f, tw2 = 0.f, tw3 = 0.f;
    float lg = -INFINITY;

    if (valid) {
        float xs = (gx + 1.0f) * 0.5f * 351.0f;
        float ys = (gy + 1.0f) * 0.5f * 127.0f;
        float xf = floorf(xs), yf = floorf(ys);
        int x0 = (int)xf, y0 = (int)yf;
        float wx = xs - xf, wy = ys - yf;
        int x1 = (x0 < FEAT_W - 1) ? x0 + 1 : x0;
        int y1 = (y0 < FEAT_H - 1) ? y0 + 1 : y0;
        ti0 = y0 * FEAT_W + x0;  ti1 = y0 * FEAT_W + x1;
        ti2 = y1 * FEAT_W + x0;  ti3 = y1 * FEAT_W + x1;
        tw0 = (1.f - wx) * (1.f - wy);  tw1 = wx * (1.f - wy);
        tw2 = (1.f - wx) * wy;          tw3 = wx * wy;

        const float dl = log1pf(fmaxf(dep, 1e-3f));
        const _Float16* q0 = fSb + (size_t)ti0 * 64;
        const _Float16* q1 = fSb + (size_t)ti1 * 64;
        const _Float16* q2 = fSb + (size_t)ti2 * 64;
        const _Float16* q3 = fSb + (size_t)ti3 * 64;
        lg = sb2[0];
        const bool fast = (flagp[0] != 0.f);
        if (fast) {
            #pragma unroll
            for (int kc = 0; kc < 4; kc++) {
                float hid[16];
                const float4* bs = (const float4*)(baseT + h * 64 + kc * 16);
                const float4* wd = (const float4*)(wD + kc * 16);
                #pragma unroll
                for (int q4 = 0; q4 < 4; q4++) {
                    float4 bv = bs[q4], wv = wd[q4];
                    hid[4 * q4 + 0] = fmaf(dl, wv.x, bv.x);
                    hid[4 * q4 + 1] = fmaf(dl, wv.y, bv.y);
                    hid[4 * q4 + 2] = fmaf(dl, wv.z, bv.z);
                    hid[4 * q4 + 3] = fmaf(dl, wv.w, bv.w);
                }
                f16x8 a0 = *(const f16x8*)(q0 + kc * 16),  a0b = *(const f16x8*)(q0 + kc * 16 + 8);
                f16x8 a1 = *(const f16x8*)(q1 + kc * 16),  a1b = *(const f16x8*)(q1 + kc * 16 + 8);
                f16x8 a2 = *(const f16x8*)(q2 + kc * 16),  a2b = *(const f16x8*)(q2 + kc * 16 + 8);
                f16x8 a3 = *(const f16x8*)(q3 + kc * 16),  a3b = *(const f16x8*)(q3 + kc * 16 + 8);
                #pragma unroll
                for (int e = 0; e < 8; e++) {
                    hid[e]     = fmaf(tw0, (float)a0[e],  fmaf(tw1, (float)a1[e],
                                 fmaf(tw2, (float)a2[e],  fmaf(tw3, (float)a3[e],  hid[e]))));
                    hid[e + 8] = fmaf(tw0, (float)a0b[e], fmaf(tw1, (float)a1b[e],
                                 fmaf(tw2, (float)a2b[e], fmaf(tw3, (float)a3b[e], hid[e + 8]))));
                }
                const float4* s2 = (const float4*)(sw2 + kc * 16);
                #pragma unroll
                for (int q4 = 0; q4 < 4; q4++) {
                    float4 sv = s2[q4];
                    lg = fmaf(fmaxf(hid[4 * q4 + 0], 0.f), sv.x, lg);
                    lg = fmaf(fmaxf(hid[4 * q4 + 1], 0.f), sv.y, lg);
                    lg = fmaf(fmaxf(hid[4 * q4 + 2], 0.f), sv.z, lg);
                    lg = fmaf(fmaxf(hid[4 * q4 + 3], 0.f), sv.w, lg);
                }
            }
        } else {
            #pragma unroll
            for (int kc = 0; kc < 4; kc++) {
                float hid[16];
                const float4* bs = (const float4*)(baseT + h * 64 + kc * 16);
                #pragma unroll
                for (int q4 = 0; q4 < 4; q4++) {
                    float4 bv = bs[q4];
                    hid[4 * q4 + 0] = bv.x; hid[4 * q4 + 1] = bv.y;
                    hid[4 * q4 + 2] = bv.z; hid[4 * q4 + 3] = bv.w;
                }
                f16x8 a0 = *(const f16x8*)(q0 + kc * 16),  a0b = *(const f16x8*)(q0 + kc * 16 + 8);
                f16x8 a1 = *(const f16x8*)(q1 + kc * 16),  a1b = *(const f16x8*)(q1 + kc * 16 + 8);
                f16x8 a2 = *(const f16x8*)(q2 + kc * 16),  a2b = *(const f16x8*)(q2 + kc * 16 + 8);
                f16x8 a3 = *(const f16x8*)(q3 + kc * 16),  a3b = *(const f16x8*)(q3 + kc * 16 + 8);
                #pragma unroll
                for (int e = 0; e < 8; e++) {
                    hid[e]     = fmaf(tw0, (float)a0[e],  fmaf(tw1, (float)a1[e],
                                 fmaf(tw2, (float)a2[e],  fmaf(tw3, (float)a3[e],  hid[e]))));
                    hid[e + 8] = fmaf(tw0, (float)a0b[e], fmaf(tw1, (float)a1b[e],
                                 fmaf(tw2, (float)a2b[e], fmaf(tw3, (float)a3b[e], hid[e + 8]))));
                }
                for (int jj = 0; jj < 64; jj++) {
                    float hd = fmaxf(fmaf(dl, dw1[jj], db1[jj]), 0.f);
                    const float4* hr = (const float4*)(hW + jj * 64 + kc * 16);
                    #pragma unroll
                    for (int q4 = 0; q4 < 4; q4++) {
                        float4 wv = hr[q4];
                        hid[4 * q4 + 0] = fmaf(hd, wv.x, hid[4 * q4 + 0]);
                        hid[4 * q4 + 1] = fmaf(hd, wv.y, hid[4 * q4 + 1]);
                        hid[4 * q4 + 2] = fmaf(hd, wv.z, hid[4 * q4 + 2]);
                        hid[4 * q4 + 3] = fmaf(hd, wv.w, hid[4 * q4 + 3]);
                    }
                }
                const float4* s2 = (const float4*)(sw2 + kc * 16);
                #pragma unroll
                for (int q4 = 0; q4 < 4; q4++) {
                    float4 sv = s2[q4];
                    lg = fmaf(fmaxf(hid[4 * q4 + 0], 0.f), sv.x, lg);
                    lg = fmaf(fmaxf(hid[4 * q4 + 1], 0.f), sv.y, lg);
                    lg = fmaf(fmaxf(hid[4 * q4 + 2], 0.f), sv.z, lg);
                    lg = fmaf(fmaxf(hid[4 * q4 + 3], 0.f), sv.w, lg);
                }
            }
        }
    }

    slog[h][c] = lg;
    __syncthreads();
    const float l0 = slog[0][c], l1 = slog[1][c], l2v = slog[2][c];
    const float mx = fmaxf(l0, fmaxf(l1, l2v));
    float myw = 0.f;
    if (mx > -INFINITY) {
        float e0 = (l0 > -INFINITY) ? expf(l0 - mx) : 0.f;
        float e1 = (l1 > -INFINITY) ? expf(l1 - mx) : 0.f;
        float e2 = (l2v > -INFINITY) ? expf(l2v - mx) : 0.f;
        float s = e0 + e1 + e2;
        float me = (h == 0) ? e0 : (h == 1) ? e1 : e2;
        myw = me / s;
    }

    const float cw0 = myw * tw0, cw1 = myw * tw1, cw2 = myw * tw2, cw3 = myw * tw3;
    const _Float16* g0 = fHb + (size_t)ti0 * 96;
    const _Float16* g1 = fHb + (size_t)ti1 * 96;
    const _Float16* g2 = fHb + (size_t)ti2 * 96;
    const _Float16* g3 = fHb + (size_t)ti3 * 96;
    float* srow = &sacc[c][0];

    if (h == 0) {
        if (myw > 0.f) {
            #pragma unroll
            for (int c8 = 0; c8 < 12; c8++) {
                f16x8 v0 = *(const f16x8*)(g0 + c8 * 8);
                f16x8 v1 = *(const f16x8*)(g1 + c8 * 8);
                f16x8 v2 = *(const f16x8*)(g2 + c8 * 8);
                f16x8 v3 = *(const f16x8*)(g3 + c8 * 8);
                #pragma unroll
                for (int e = 0; e < 8; e++)
                    srow[c8 * 8 + e] = fmaf(cw0, (float)v0[e], fmaf(cw1, (float)v1[e],
                                       fmaf(cw2, (float)v2[e], cw3 * (float)v3[e])));
            }
        } else {
            #pragma unroll
            for (int k = 0; k < 96; k++) srow[k] = 0.f;
        }
    }
    __syncthreads();
    if (h == 1 && myw > 0.f) {
        #pragma unroll
        for (int c8 = 0; c8 < 12; c8++) {
            f16x8 v0 = *(const f16x8*)(g0 + c8 * 8);
            f16x8 v1 = *(const f16x8*)(g1 + c8 * 8);
            f16x8 v2 = *(const f16x8*)(g2 + c8 * 8);
            f16x8 v3 = *(const f16x8*)(g3 + c8 * 8);
            #pragma unroll
            for (int e = 0; e < 8; e++)
                srow[c8 * 8 + e] += fmaf(cw0, (float)v0[e], fmaf(cw1, (float)v1[e],
                                    fmaf(cw2, (float)v2[e], cw3 * (float)v3[e])));
        }
    }
    __syncthreads();
    if (h == 2 && myw > 0.f) {
        #pragma unroll
        for (int c8 = 0; c8 < 12; c8++) {
            f16x8 v0 = *(const f16x8*)(g0 + c8 * 8);
            f16x8 v1 = *(const f16x8*)(g1 + c8 * 8);
            f16x8 v2 = *(const f16x8*)(g2 + c8 * 8);
            f16x8 v3 = *(const f16x8*)(g3 + c8 * 8);
            #pragma unroll
            for (int e = 0; e < 8; e++)
                srow[c8 * 8 + e] += fmaf(cw0, (float)v0[e], fmaf(cw1, (float)v1[e],
                                    fmaf(cw2, (float)v2[e], cw3 * (float)v3[e])));
        }
    }
    __syncthreads();

    if (h == 0) {
        _Float16* op = out + ((size_t)(b * PD + i + 1) * PD + (j + 1)) * CH;
        #pragma unroll
        for (int c8 = 0; c8 < 12; ++c8) {
            f16x8 v;
            #pragma unroll
            for (int e = 0; e < 8; ++e) v[e] = (_Float16)srow[c8 * 8 + e];
            *(f16x8*)(op + c8 * 8) = v;
        }
    }
}

// ---------------------------------------------------------------------------
// Conv 3x3 + BN + ReLU, f16 MFMA implicit GEMM, explicit depth-2 pipeline.
// Block: 8 rows x 32 cols, 4 waves; wave = 4 pixel-tiles x 6 oc-tiles.
// A operand = weights (global, L2-hot), B = pixels (LDS halo tile).
// 3 rotating fragment slots; at each MFMA group, 2 steps of loads in flight.
// ---------------------------------------------------------------------------
#define LOAD_FRAGS(WF, PF, STEP) do {                                              \
    constexpr int _tap = (STEP) / 3, _kc = (STEP) % 3;                             \
    constexpr int _r = _tap / 3, _s = _tap % 3;                                    \
    _Pragma("unroll")                                                              \
    for (int ot = 0; ot < 6; ++ot)                                                 \
        WF[ot] = *(const f16x8*)(wtb + _tap * 9216 + ot * 1536 + _kc * 32);        \
    _Pragma("unroll")                                                              \
    for (int pt = 0; pt < 4; ++pt)                                                 \
        PF[pt] = *(const f16x8*)(&sA[((2 * w + (pt >> 1) + _r) * 34                \
                         + (pt & 1) * 16 + _s + n) * 104 + _kc * 32 + q * 8]);     \
} while (0)

#define DO_MFMA(WF, PF) do {                                                       \
    _Pragma("unroll")                                                              \
    for (int ot = 0; ot < 6; ++ot)                                                 \
        _Pragma("unroll")                                                          \
        for (int pt = 0; pt < 4; ++pt)                                             \
            acc[ot][pt] = __builtin_amdgcn_mfma_f32_16x16x32_f16(                  \
                              WF[ot], PF[pt], acc[ot][pt], 0, 0, 0);               \
} while (0)

#define TRIPLE(S)                                                                  \
    LOAD_FRAGS(wfc, pfc, (S) + 2); DO_MFMA(wfa, pfa);                              \
    LOAD_FRAGS(wfa, pfa, (S) + 3); DO_MFMA(wfb, pfb);                              \
    LOAD_FRAGS(wfb, pfb, (S) + 4); DO_MFMA(wfc, pfc);

template<int MODE>
__global__ __launch_bounds__(256, 2) void k_conv_mfma(
        const _Float16* __restrict__ in, const _Float16* __restrict__ wt,
        const float* __restrict__ bng, const float* __restrict__ bnb,
        const float* __restrict__ bnm, const float* __restrict__ bnv,
        void* __restrict__ outv) {
    __shared__ _Float16 sA[10 * 34 * 104];   // 70,720 B
    const int tid = threadIdx.x;
    const int w = tid >> 6, lane = tid & 63, q = lane >> 4, n = lane & 15;
    const int x0 = blockIdx.x * 32, y0 = blockIdx.y * 8, b = blockIdx.z;
    const _Float16* inb = in + (size_t)b * PPIX * CH;

    for (int idx = tid; idx < 10 * 34 * 12; idx += 256) {
        int pix = idx / 12, c8 = idx - pix * 12;
        int rr = pix / 34, cc = pix - rr * 34;
        *(f16x8*)(&sA[pix * 104 + c8 * 8]) =
            *(const f16x8*)(inb + ((size_t)(y0 + rr) * PD + (x0 + cc)) * CH + c8 * 8);
    }
    __syncthreads();

    f32x4 acc[6][4];
    #pragma unroll
    for (int ot = 0; ot < 6; ot++)
        #pragma unroll
        for (int pt = 0; pt < 4; pt++) acc[ot][pt] = (f32x4){0.f, 0.f, 0.f, 0.f};

    const _Float16* wtb = wt + n * CH + q * 8;

    f16x8 wfa[6], wfb[6], wfc[6], pfa[4], pfb[4], pfc[4];
    LOAD_FRAGS(wfa, pfa, 0);
    LOAD_FRAGS(wfb, pfb, 1);
    TRIPLE(0)  TRIPLE(3)  TRIPLE(6)  TRIPLE(9)
    TRIPLE(12) TRIPLE(15) TRIPLE(18) TRIPLE(21)
    LOAD_FRAGS(wfc, pfc, 26); DO_MFMA(wfa, pfa);   // step 24
    DO_MFMA(wfb, pfb);                              // step 25
    DO_MFMA(wfc, pfc);                              // step 26

    float scv[6][4], shv[6][4];
    #pragma unroll
    for (int ot = 0; ot < 6; ot++)
        #pragma unroll
        for (int rg = 0; rg < 4; rg++) {
            int oc = ot * 16 + q * 4 + rg;
            scv[ot][rg] = bng[oc] * rsqrtf(bnv[oc] + 1e-3f);
            shv[ot][rg] = fmaf(-bnm[oc], scv[ot][rg], bnb[oc]);
        }

    if (MODE == 0) {
        _Float16* outb = (_Float16*)outv + (size_t)b * PPIX * CH;
        #pragma unroll
        for (int pt = 0; pt < 4; pt++) {
            const int orow = y0 + 2 * w + (pt >> 1) + 1;
            const int ocol = x0 + (pt & 1) * 16 + n + 1;
            _Float16* op = outb + ((size_t)orow * PD + ocol) * CH + q * 4;
            #pragma unroll
            for (int ot = 0; ot < 6; ot++) {
                f16x4 pv;
                #pragma unroll
                for (int rg = 0; rg < 4; rg++)
                    pv[rg] = (_Float16)fmaxf(fmaf(acc[ot][pt][rg], scv[ot][rg], shv[ot][rg]), 0.f);
                *(f16x4*)(op + ot * 16) = pv;
            }
        }
    } else {
        float* outb = (float*)outv + (size_t)b * CH * NCELL;
        #pragma unroll
        for (int pt = 0; pt < 4; pt++) {
            const int prow = y0 + 2 * w + (pt >> 1);
            const int pcol = x0 + (pt & 1) * 16 + n;
            #pragma unroll
            for (int ot = 0; ot < 6; ot++)
                #pragma unroll
                for (int rg = 0; rg < 4; rg++) {
                    int oc = ot * 16 + q * 4 + rg;
                    outb[(size_t)oc * NCELL + prow * BEV + pcol] =
                        fmaxf(fmaf(acc[ot][pt][rg], scv[ot][rg], shv[ot][rg]), 0.f);
                }
        }
    }
}

// ---------------------------------------------------------------------------
extern "C" void kernel_launch(void* const* d_in, const int* in_sizes, int n_in,
                              void* d_out, int out_size, void* d_ws, size_t ws_size,
                              hipStream_t stream) {
    const float* feat = (const float*)d_in[0];
    const float* l2i  = (const float*)d_in[1];
    const float* he   = (const float*)d_in[2];
    const float* dw1  = (const float*)d_in[3];
    const float* db1  = (const float*)d_in[4];
    const float* dw2  = (const float*)d_in[5];
    const float* db2  = (const float*)d_in[6];
    const float* sw1  = (const float*)d_in[7];
    const float* sb1  = (const float*)d_in[8];
    const float* sw2  = (const float*)d_in[9];
    const float* sb2  = (const float*)d_in[10];
    const float* c1w  = (const float*)d_in[11];
    const float* bn1g = (const float*)d_in[12];
    const float* bn1b = (const float*)d_in[13];
    const float* bn1m = (const float*)d_in[14];
    const float* bn1v = (const float*)d_in[15];
    const float* c2w  = (const float*)d_in[16];
    const float* bn2g = (const float*)d_in[17];
    const float* bn2b = (const float*)d_in[18];
    const float* bn2m = (const float*)d_in[19];
    const float* bn2v = (const float*)d_in[20];

    float* ws = (float*)d_ws;
    _Float16*  bufB   = (_Float16*)(ws + OFF_BUFB);
    _Float16*  featS  = (_Float16*)(ws + OFF_FS);   // aliases bufB (dead before conv1)
    _Float16*  featH  = (_Float16*)(ws + OFF_FH);   // aliases bufB (dead before conv1)
    _Float16*  wtp    = (_Float16*)(ws + OFF_WT);
    float*     hW     = ws + OFF_HW;
    float*     baseT  = ws + OFF_BASE;
    float*     wD     = ws + OFF_WD;
    float*     flagp  = ws + OFF_FLAG;
    _Float16*  bufA   = (_Float16*)(ws + OFF_BUFA);
    _Float16*  wt1    = wtp;
    _Float16*  wt2    = wtp + 82944;

    hipLaunchKernelGGL(k_setup, dim3(660), dim3(256), 0, stream,
                       dw2, sw1, db2, he, sb1, dw1, db1, c1w, c2w,
                       hW, baseT, wD, flagp, wtp, bufA);
    hipLaunchKernelGGL(k_feats, dim3(FPIX / 64, 2), dim3(64), 0, stream,
                       feat, sw1, featS, featH);
    hipLaunchKernelGGL(k_lift, dim3(NCELL / 128, 2), dim3(384), 0, stream,
                       featS, featH, l2i, dw1, db1, sw2, sb2, hW, baseT, wD, flagp, bufA);
    // bufB borders only after k_lift (featS/featH alias bufB)
    hipLaunchKernelGGL(k_border, dim3(11), dim3(256), 0, stream, bufB);
    hipLaunchKernelGGL((k_conv_mfma<0>), dim3(10, 40, 2), dim3(256), 0, stream,
                       bufA, wt1, bn1g, bn1b, bn1m, bn1v, (void*)bufB);
    hipLaunchKernelGGL((k_conv_mfma<1>), dim3(10, 40, 2), dim3(256), 0, stream,
                       bufB, wt2, bn2g, bn2b, bn2m, bn2v, d_out);
}